// Round 12
// baseline (323.705 us; speedup 1.0000x reference)
//
#include <hip/hip_runtime.h>
#include <math.h>

#define DIM 768
#define HEADS 12
#define DHEAD 64
#define NTOK 31
#define BATCH 512
#define MTOK (BATCH * NTOK)   /* 15872 */
#define HIDDEN 3072
#define QKVN 2304
#define MASK_VAL -987654321.0f

typedef short s16x8 __attribute__((ext_vector_type(8)));
typedef float f32x4 __attribute__((ext_vector_type(4)));

static __device__ __forceinline__ float bs2f(unsigned short u) {
  unsigned int x = ((unsigned int)u) << 16;
  return __builtin_bit_cast(float, x);
}
static __device__ __forceinline__ unsigned short f2bs(float f) {
  unsigned int x = __builtin_bit_cast(unsigned int, f);
  x += 0x7fffu + ((x >> 16) & 1u);
  return (unsigned short)(x >> 16);
}

// async global->LDS, 16B per lane, wave-uniform LDS base + lane*16
static __device__ __forceinline__ void gload16(const unsigned short* g, unsigned short* l) {
  __builtin_amdgcn_global_load_lds(
      (const __attribute__((address_space(1))) unsigned int*)g,
      (__attribute__((address_space(3))) unsigned int*)l, 16, 0, 0);
}

static __device__ __forceinline__ float epi_apply(int EPI, float v, int col, size_t idx,
                                                  const float* bias, const void* resid) {
  if (EPI == 0) return v;
  if (EPI == 2) {
    float t = v + bias[col];
    float arg = 1.5957691216f * t * (1.f + 0.044715f * t * t);
    return t * __builtin_amdgcn_rcpf(1.f + __expf(-arg));
  }
  if (EPI == 3) return v + bias[col] + ((const float*)resid)[idx];
  return v + bias[col] + bs2f(((const unsigned short*)resid)[idx]);  // EPI==4
}

static __device__ __forceinline__ void epi_store(int EPI, void* outp, size_t idx, float t) {
  if (EPI == 4) ((float*)outp)[idx] = t;
  else ((unsigned short*)outp)[idx] = f2bs(t);
}

// ---------------- batched weight transposes: all 4 in one launch ----------------
__global__ __launch_bounds__(256) void transpose_all_kernel(
    const float* __restrict__ w_qkv, const float* __restrict__ w_o,
    const float* __restrict__ w1, const float* __restrict__ w2,
    unsigned short* __restrict__ wqkvT, unsigned short* __restrict__ woT,
    unsigned short* __restrict__ w1T, unsigned short* __restrict__ w2T) {
  int t = blockIdx.x;
  const float* w;
  unsigned short* wt;
  int K, N, tx;
  if (t < 432) { w = w_qkv; wt = wqkvT; K = DIM; N = QKVN; tx = QKVN / 64; }
  else if (t < 576) { t -= 432; w = w_o; wt = woT; K = DIM; N = DIM; tx = DIM / 64; }
  else if (t < 1152) { t -= 576; w = w1; wt = w1T; K = DIM; N = HIDDEN; tx = HIDDEN / 64; }
  else { t -= 1152; w = w2; wt = w2T; K = HIDDEN; N = DIM; tx = DIM / 64; }
  int n0 = (t % tx) * 64, k0 = (t / tx) * 64;

  __shared__ float tl[64][65];
  int tid = threadIdx.x;
  int r = tid >> 4, c4 = (tid & 15) * 4;
#pragma unroll
  for (int i = 0; i < 4; ++i) {
    float4 v = *(const float4*)(w + (size_t)(k0 + r + i * 16) * N + n0 + c4);
    tl[r + i * 16][c4] = v.x;
    tl[r + i * 16][c4 + 1] = v.y;
    tl[r + i * 16][c4 + 2] = v.z;
    tl[r + i * 16][c4 + 3] = v.w;
  }
  __syncthreads();
#pragma unroll
  for (int i = 0; i < 4; ++i) {
    int n = r + i * 16;
    ushort4 o;
    o.x = f2bs(tl[c4 + 0][n]);
    o.y = f2bs(tl[c4 + 1][n]);
    o.z = f2bs(tl[c4 + 2][n]);
    o.w = f2bs(tl[c4 + 3][n]);
    *(ushort4*)(wt + (size_t)(n0 + n) * K + k0 + c4) = o;
  }
}

// ---------------- LayerNorm (f32 in) ----------------
__global__ __launch_bounds__(256) void ln_kernel(const float* __restrict__ x,
                                                 const float* __restrict__ g,
                                                 const float* __restrict__ bta,
                                                 unsigned short* __restrict__ out) {
  int wid = threadIdx.x >> 6, lane = threadIdx.x & 63;
  size_t row = (size_t)blockIdx.x * 4 + wid;
  const float4* xr = (const float4*)(x + row * DIM);
  float4 v[3];
  v[0] = xr[lane];
  v[1] = xr[lane + 64];
  v[2] = xr[lane + 128];
  float s = 0.f, sq = 0.f;
#pragma unroll
  for (int i = 0; i < 3; ++i) {
    s += v[i].x + v[i].y + v[i].z + v[i].w;
    sq += v[i].x * v[i].x + v[i].y * v[i].y + v[i].z * v[i].z + v[i].w * v[i].w;
  }
#pragma unroll
  for (int off = 32; off; off >>= 1) {
    s += __shfl_xor(s, off);
    sq += __shfl_xor(sq, off);
  }
  float mu = s * (1.f / DIM);
  float var = sq * (1.f / DIM) - mu * mu;
  float rs = rsqrtf(var + 1e-5f);
#pragma unroll
  for (int i = 0; i < 3; ++i) {
    int col = i * 256 + lane * 4;
    float4 gg = *(const float4*)(g + col);
    float4 bb = *(const float4*)(bta + col);
    ushort4 o;
    o.x = f2bs((v[i].x - mu) * rs * gg.x + bb.x);
    o.y = f2bs((v[i].y - mu) * rs * gg.y + bb.y);
    o.z = f2bs((v[i].z - mu) * rs * gg.z + bb.z);
    o.w = f2bs((v[i].w - mu) * rs * gg.w + bb.w);
    *(ushort4*)(out + row * DIM + col) = o;
  }
}

// ---------------- LayerNorm (bf16 in) ----------------
__global__ __launch_bounds__(256) void ln_bf16_kernel(const unsigned short* __restrict__ x,
                                                      const float* __restrict__ g,
                                                      const float* __restrict__ bta,
                                                      unsigned short* __restrict__ out) {
  int wid = threadIdx.x >> 6, lane = threadIdx.x & 63;
  size_t row = (size_t)blockIdx.x * 4 + wid;
  const unsigned short* xr = x + row * DIM;
  float v[12];
#pragma unroll
  for (int i = 0; i < 3; ++i) {
    ushort4 u = *(const ushort4*)(xr + i * 256 + lane * 4);
    v[i * 4 + 0] = bs2f(u.x);
    v[i * 4 + 1] = bs2f(u.y);
    v[i * 4 + 2] = bs2f(u.z);
    v[i * 4 + 3] = bs2f(u.w);
  }
  float s = 0.f, sq = 0.f;
#pragma unroll
  for (int i = 0; i < 12; ++i) {
    s += v[i];
    sq += v[i] * v[i];
  }
#pragma unroll
  for (int off = 32; off; off >>= 1) {
    s += __shfl_xor(s, off);
    sq += __shfl_xor(sq, off);
  }
  float mu = s * (1.f / DIM);
  float var = sq * (1.f / DIM) - mu * mu;
  float rs = rsqrtf(var + 1e-5f);
#pragma unroll
  for (int i = 0; i < 3; ++i) {
    int col = i * 256 + lane * 4;
    float4 gg = *(const float4*)(g + col);
    float4 bb = *(const float4*)(bta + col);
    ushort4 o;
    o.x = f2bs((v[i * 4 + 0] - mu) * rs * gg.x + bb.x);
    o.y = f2bs((v[i * 4 + 1] - mu) * rs * gg.y + bb.y);
    o.z = f2bs((v[i * 4 + 2] - mu) * rs * gg.z + bb.z);
    o.w = f2bs((v[i * 4 + 3] - mu) * rs * gg.w + bb.w);
    *(ushort4*)(out + row * DIM + col) = o;
  }
}

// ================= merged-phase 128x256 BK=32 GEMM (qkv, mlp1; K==768 -> NT=24) =================
// One barrier-pair per K-step: 8 ds_read_b128 + stage + vmcnt(2) + barrier + lgkm(0)
// + 16 MFMA + barrier. A 2-deep (2x8KB @0), B 3-deep ring (3x16KB @16384) -> 64KB LDS,
// 2 blocks/CU. Ledger: phase t reads A[t&1],B[t%3]; stages A(t+1),B(t+2); steady
// vmcnt(2) retires exactly {A(t+1),B(t+1)}, leaves B(t+2) in flight. Tail: t=22
// stages A23 only -> vmcnt(0); t=23 no stage/wait.
template <int AB, int BB, int VM, typename STF>
__device__ __forceinline__ void gphm(const char* aBase, const char* bBase,
                                     f32x4 (&acc)[4][4], STF&& stage) {
  const char* aP = aBase + AB * 8192;
  const char* bP = bBase + BB * 16384;
  s16x8 af[4], bk[4];
#pragma unroll
  for (int ni = 0; ni < 4; ++ni) bk[ni] = *(const s16x8*)(bP + ni * 1024);
#pragma unroll
  for (int mi = 0; mi < 4; ++mi) af[mi] = *(const s16x8*)(aP + mi * 1024);
  stage();
  if (VM == 2) asm volatile("s_waitcnt vmcnt(2)");
  if (VM == 0) asm volatile("s_waitcnt vmcnt(0)");
  __builtin_amdgcn_s_barrier();
  asm volatile("s_waitcnt lgkmcnt(0)");
  __builtin_amdgcn_s_setprio(1);
#pragma unroll
  for (int mi = 0; mi < 4; ++mi)
#pragma unroll
    for (int ni = 0; ni < 4; ++ni)
      acc[mi][ni] =
          __builtin_amdgcn_mfma_f32_16x16x32_bf16(af[mi], bk[ni], acc[mi][ni], 0, 0, 0);
  __builtin_amdgcn_s_setprio(0);
  __builtin_amdgcn_s_barrier();
}

template <int EPI>
__device__ __forceinline__ void gemm128m_body(
    const unsigned short* __restrict__ A, const unsigned short* __restrict__ Bt,
    void* __restrict__ outp, const float* __restrict__ bias,
    const void* __restrict__ resid, int M, int N, int K, int ntn) {
  __shared__ char ldsc[65536];  // 64 KiB: A 2x8KB @0, B 3x16KB @16384
  int tid = threadIdx.x;
  int lane = tid & 63, w = tid >> 6;
  int wm = w >> 2, wn = w & 3;
  int fr = lane & 15, q = lane >> 4;

  int nwg = gridDim.x, orig = blockIdx.x;
  int qd = nwg >> 3, r8 = nwg & 7, xcd = orig & 7, loc = orig >> 3;
  int bid = (xcd < r8 ? xcd * (qd + 1) : r8 * (qd + 1) + (xcd - r8) * qd) + loc;
  int m0 = (bid / ntn) * 128, n0 = (bid % ntn) * 256;

  int rdoff = (q * 16) ^ (((fr >> 1) & 3) << 4);
  const char* aBase = ldsc + (wm * 64 + fr) * 64 + rdoff;
  const char* bBase = ldsc + 16384 + (wn * 64 + fr) * 64 + rdoff;

  int srow = tid >> 2;  // 0..127
  int seoff = (((tid & 3) ^ ((srow >> 1) & 3))) << 3;
  const char* Ab = (const char*)A + ((size_t)(m0 + srow) * K + seoff) * 2;
  const char* Bb = (const char*)Bt + ((size_t)(n0 + srow) * K + seoff) * 2;
  size_t rstep = (size_t)K * 256;  // 128 rows of bf16

  auto stgA = [&](int buf, int tile) {
    gload16((const unsigned short*)(Ab + tile * 64),
            (unsigned short*)(ldsc + buf * 8192 + w * 1024));
  };
  auto stgB = [&](int buf, int tile) {
    const char* gp = Bb + tile * 64;
    char* lp = ldsc + 16384 + buf * 16384 + w * 1024;
    gload16((const unsigned short*)gp, (unsigned short*)lp);
    gload16((const unsigned short*)(gp + rstep), (unsigned short*)(lp + 8192));
  };
  auto nop = [&] {};

  f32x4 acc[4][4] = {};
  // NT = 24 (K == 768). Prologue: A0, B0, B1; wait A0,B0.
  stgA(0, 0);
  stgB(0, 0);
  stgB(1, 1);
  asm volatile("s_waitcnt vmcnt(2)");
  __builtin_amdgcn_s_barrier();

#pragma unroll 1
  for (int T = 0; T < 18; T += 6) {
    gphm<0, 0, 2>(aBase, bBase, acc, [&] { stgA(1, T + 1); stgB(2, T + 2); });
    gphm<1, 1, 2>(aBase, bBase, acc, [&] { stgA(0, T + 2); stgB(0, T + 3); });
    gphm<0, 2, 2>(aBase, bBase, acc, [&] { stgA(1, T + 3); stgB(1, T + 4); });
    gphm<1, 0, 2>(aBase, bBase, acc, [&] { stgA(0, T + 4); stgB(2, T + 5); });
    gphm<0, 1, 2>(aBase, bBase, acc, [&] { stgA(1, T + 5); stgB(0, T + 6); });
    gphm<1, 2, 2>(aBase, bBase, acc, [&] { stgA(0, T + 6); stgB(1, T + 7); });
  }
  // tail: t = 18..23
  gphm<0, 0, 2>(aBase, bBase, acc, [&] { stgA(1, 19); stgB(2, 20); });
  gphm<1, 1, 2>(aBase, bBase, acc, [&] { stgA(0, 20); stgB(0, 21); });
  gphm<0, 2, 2>(aBase, bBase, acc, [&] { stgA(1, 21); stgB(1, 22); });
  gphm<1, 0, 2>(aBase, bBase, acc, [&] { stgA(0, 22); stgB(2, 23); });
  gphm<0, 1, 0>(aBase, bBase, acc, [&] { stgA(1, 23); });
  gphm<1, 2, -1>(aBase, bBase, acc, nop);

#pragma unroll
  for (int am = 0; am < 4; ++am)
#pragma unroll
    for (int ni = 0; ni < 4; ++ni)
#pragma unroll
      for (int rr = 0; rr < 4; ++rr) {
        int row = m0 + wm * 64 + am * 16 + q * 4 + rr;
        int col = n0 + wn * 64 + ni * 16 + fr;
        size_t idx = (size_t)row * N + col;
        epi_store(EPI, outp, idx, epi_apply(EPI, acc[am][ni][rr], col, idx, bias, resid));
      }
}

// ================= 8-phase 256x192 GEMM (fill path: proj, mlp2) =================
template <int BUF, int MH, int KH, int VM, typename STF>
__device__ __forceinline__ void gph192(const char* aB0, const char* bKH0, const char* bKH1,
                                       s16x8 (&bk)[3], f32x4 (&acc)[8][3], STF&& stage) {
  const char* aP = aB0 + BUF * 32768 + KH * 16384 + MH * 4096;
  s16x8 af[4];
  if (MH == 0) {
    const char* bp = (KH ? bKH1 : bKH0) + BUF * 24576;
#pragma unroll
    for (int ni = 0; ni < 3; ++ni) bk[ni] = *(const s16x8*)(bp + ni * 2048);
  }
#pragma unroll
  for (int mi = 0; mi < 4; ++mi) af[mi] = *(const s16x8*)(aP + mi * 1024);
  stage();
  if (VM == 2) asm volatile("s_waitcnt vmcnt(2)");
  if (VM == 0) asm volatile("s_waitcnt vmcnt(0)");
  __builtin_amdgcn_s_barrier();
  asm volatile("s_waitcnt lgkmcnt(0)");
  __builtin_amdgcn_s_setprio(1);
#pragma unroll
  for (int mi = 0; mi < 4; ++mi)
#pragma unroll
    for (int ni = 0; ni < 3; ++ni)
      acc[MH * 4 + mi][ni] =
          __builtin_amdgcn_mfma_f32_16x16x32_bf16(af[mi], bk[ni], acc[MH * 4 + mi][ni], 0, 0, 0);
  __builtin_amdgcn_s_setprio(0);
  __builtin_amdgcn_s_barrier();
}

template <int EPI>
__device__ __forceinline__ void gemm192_body(
    const unsigned short* __restrict__ A, const unsigned short* __restrict__ Bt,
    void* __restrict__ outp, const float* __restrict__ bias,
    const void* __restrict__ resid, int M, int N, int K, int ntn) {
  __shared__ char ldsc[114688];  // 112 KiB
  int tid = threadIdx.x;
  int lane = tid & 63, w = tid >> 6;
  int wm = w >> 2, wn = w & 3;
  int fr = lane & 15, q = lane >> 4;

  int nwg = gridDim.x, orig = blockIdx.x;
  int qd = nwg >> 3, r8 = nwg & 7, xcd = orig & 7, loc = orig >> 3;
  int bid = (xcd < r8 ? xcd * (qd + 1) : r8 * (qd + 1) + (xcd - r8) * qd) + loc;
  int m0 = (bid / ntn) * 256, n0 = (bid % ntn) * 192;

  int rdoffA = (q * 16) ^ (((fr >> 1) & 3) << 4);
  const char* aB0 = ldsc + (wm * 128 + fr) * 64 + rdoffA;
  int brow0 = wn * 48 + fr;
  int bsw = brow0 & 7;
  const char* bBase = ldsc + 65536 + brow0 * 128 + (q ^ (bsw & 3)) * 16;
  const char* bKH0 = bBase + ((0 ^ (bsw >> 2)) * 64);
  const char* bKH1 = bBase + ((1 ^ (bsw >> 2)) * 64);

  int srow = tid >> 2;
  int seoffA = (((tid & 3) ^ ((srow >> 1) & 3))) << 3;
  const char* Ab = (const char*)A + ((size_t)(m0 + srow) * K + seoffA) * 2;
  size_t rstep = (size_t)K * 256;
  auto stgA = [&](int kh, int buf, int tile) {
    const char* gp = Ab + tile * 128 + kh * 64;
    unsigned short* lp = (unsigned short*)(ldsc + buf * 32768 + kh * 16384 + w * 1024);
    gload16((const unsigned short*)gp, lp);
    gload16((const unsigned short*)(gp + rstep), (unsigned short*)((char*)lp + 8192));
  };
  const char* Bb2 = (const char*)Bt +
                    ((size_t)(n0 + (tid >> 3)) * K + (((tid & 7) ^ ((tid >> 3) & 7)) * 8)) * 2;
  auto stgB = [&](int j, int buf, int tile) {
    gload16((const unsigned short*)(Bb2 + (size_t)j * 128 * K + tile * 128),
            (unsigned short*)(ldsc + 65536 + buf * 24576 + j * 8192 + w * 1024));
  };
  auto nop = [&] {};

  f32x4 acc[8][3] = {};
  s16x8 bk[3];
  int NT = K / 64;

  stgA(0, 0, 0);
  stgA(1, 0, 0);
  stgB(0, 0, 0);
  stgB(1, 0, 0);
  stgB(2, 0, 0);
  stgA(0, 1, 1);
  asm volatile("s_waitcnt vmcnt(2)");
  __builtin_amdgcn_s_barrier();

  for (int t = 0; t + 3 < NT; t += 2) {
    gph192<0, 0, 0, -1>(aB0, bKH0, bKH1, bk, acc,
                        [&] { stgA(1, 1, t + 1); stgB(0, 1, t + 1); stgB(1, 1, t + 1); });
    gph192<0, 1, 0, -1>(aB0, bKH0, bKH1, bk, acc, [&] { stgB(2, 1, t + 1); });
    gph192<0, 0, 1, -1>(aB0, bKH0, bKH1, bk, acc, [&] { stgA(0, 0, t + 2); });
    gph192<0, 1, 1, 2>(aB0, bKH0, bKH1, bk, acc, nop);
    gph192<1, 0, 0, -1>(aB0, bKH0, bKH1, bk, acc,
                        [&] { stgA(1, 0, t + 2); stgB(0, 0, t + 2); stgB(1, 0, t + 2); });
    gph192<1, 1, 0, -1>(aB0, bKH0, bKH1, bk, acc, [&] { stgB(2, 0, t + 2); });
    gph192<1, 0, 1, -1>(aB0, bKH0, bKH1, bk, acc, [&] { stgA(0, 1, t + 3); });
    gph192<1, 1, 1, 2>(aB0, bKH0, bKH1, bk, acc, nop);
  }
  gph192<0, 0, 0, -1>(aB0, bKH0, bKH1, bk, acc,
                      [&] { stgA(1, 1, NT - 1); stgB(0, 1, NT - 1); stgB(1, 1, NT - 1); });
  gph192<0, 1, 0, -1>(aB0, bKH0, bKH1, bk, acc, [&] { stgB(2, 1, NT - 1); });
  gph192<0, 0, 1, -1>(aB0, bKH0, bKH1, bk, acc, nop);
  gph192<0, 1, 1, 0>(aB0, bKH0, bKH1, bk, acc, nop);
  gph192<1, 0, 0, -1>(aB0, bKH0, bKH1, bk, acc, nop);
  gph192<1, 1, 0, -1>(aB0, bKH0, bKH1, bk, acc, nop);
  gph192<1, 0, 1, -1>(aB0, bKH0, bKH1, bk, acc, nop);
  gph192<1, 1, 1, -1>(aB0, bKH0, bKH1, bk, acc, nop);

#pragma unroll
  for (int am = 0; am < 8; ++am)
#pragma unroll
    for (int ni = 0; ni < 3; ++ni)
#pragma unroll
      for (int rr = 0; rr < 4; ++rr) {
        int row = m0 + wm * 128 + am * 16 + q * 4 + rr;
        int col = n0 + wn * 48 + ni * 16 + fr;
        size_t idx = (size_t)row * N + col;
        epi_store(EPI, outp, idx, epi_apply(EPI, acc[am][ni][rr], col, idx, bias, resid));
      }
}

// named wrappers for rocprof attribution
__global__ __launch_bounds__(512, 4) void gemm_qkv(const unsigned short* A,
                                                   const unsigned short* Bt, void* o,
                                                   const float* b, const void* r, int M,
                                                   int N, int K, int ntn) {
  gemm128m_body<0>(A, Bt, o, b, r, M, N, K, ntn);
}
__global__ __launch_bounds__(512, 4) void gemm_mlp1(const unsigned short* A,
                                                    const unsigned short* Bt, void* o,
                                                    const float* b, const void* r, int M,
                                                    int N, int K, int ntn) {
  gemm128m_body<2>(A, Bt, o, b, r, M, N, K, ntn);
}
__global__ __launch_bounds__(512, 2) void gemm_proj(const unsigned short* A,
                                                    const unsigned short* Bt, void* o,
                                                    const float* b, const void* r, int M,
                                                    int N, int K, int ntn) {
  gemm192_body<3>(A, Bt, o, b, r, M, N, K, ntn);
}
__global__ __launch_bounds__(512, 2) void gemm_mlp2(const unsigned short* A,
                                                    const unsigned short* Bt, void* o,
                                                    const float* b, const void* r, int M,
                                                    int N, int K, int ntn) {
  gemm192_body<4>(A, Bt, o, b, r, M, N, K, ntn);
}

// ---------------- MFMA attention: one wave per (batch, head) ----------------
__global__ __launch_bounds__(256) void attn_mfma_kernel(const unsigned short* __restrict__ qkv,
                                                        const float* __restrict__ scale,
                                                        unsigned short* __restrict__ ao) {
  __shared__ unsigned short Vt[4][64][40];
  __shared__ unsigned short Pl[4][32][32];
  int wid = threadIdx.x >> 6, lane = threadIdx.x & 63;
  int pair = blockIdx.x * 4 + wid;
  int b = pair / HEADS, h = pair % HEADS;
  const unsigned short* base = qkv + (size_t)b * NTOK * QKVN + h * DHEAD;
  const unsigned short* Qp = base;
  const unsigned short* Kp = base + 768;
  const unsigned short* Vp = base + 1536;

  int c = lane & 15, q = lane >> 4;
  int oct = q * 8;

  unsigned short vcol[NTOK];
#pragma unroll
  for (int j = 0; j < NTOK; ++j) vcol[j] = Vp[(size_t)j * QKVN + lane];
#pragma unroll
  for (int j = 0; j < NTOK; ++j) Vt[wid][lane][j] = vcol[j];
  Vt[wid][lane][31] = 0;

  s16x8 kf[2][2] = {{{0}}}, qf[2][2] = {{{0}}};
#pragma unroll
  for (int t = 0; t < 2; ++t) {
    int row = t * 16 + c;
    if (row < NTOK) {
#pragma unroll
      for (int s = 0; s < 2; ++s) {
        kf[t][s] = *(const s16x8*)(Kp + (size_t)row * QKVN + s * 32 + oct);
        qf[t][s] = *(const s16x8*)(Qp + (size_t)row * QKVN + s * 32 + oct);
      }
    }
  }

  f32x4 st[2][2] = {};
#pragma unroll
  for (int jt = 0; jt < 2; ++jt)
#pragma unroll
    for (int it = 0; it < 2; ++it)
#pragma unroll
      for (int s = 0; s < 2; ++s)
        st[jt][it] =
            __builtin_amdgcn_mfma_f32_16x16x32_bf16(kf[jt][s], qf[it][s], st[jt][it], 0, 0, 0);

  float scl = scale[h];
  float p[2][2][4];
#pragma unroll
  for (int it = 0; it < 2; ++it)
#pragma unroll
    for (int jt = 0; jt < 2; ++jt)
#pragma unroll
      for (int r = 0; r < 4; ++r) {
        int j = jt * 16 + 4 * q + r;
        int i = it * 16 + c;
        float v = st[jt][it][r] * scl;
        if (j == 31 || j == i) v = MASK_VAL;
        p[it][jt][r] = v;
      }
#pragma unroll
  for (int it = 0; it < 2; ++it) {
    float m = p[it][0][0];
#pragma unroll
    for (int jt = 0; jt < 2; ++jt)
#pragma unroll
      for (int r = 0; r < 4; ++r) m = fmaxf(m, p[it][jt][r]);
    m = fmaxf(m, __shfl_xor(m, 16));
    m = fmaxf(m, __shfl_xor(m, 32));
    float s = 0.f;
#pragma unroll
    for (int jt = 0; jt < 2; ++jt)
#pragma unroll
      for (int r = 0; r < 4; ++r) {
        float e = __expf(p[it][jt][r] - m);
        p[it][jt][r] = e;
        s += e;
      }
    s += __shfl_xor(s, 16);
    s += __shfl_xor(s, 32);
    float inv = __builtin_amdgcn_rcpf(s);
#pragma unroll
    for (int jt = 0; jt < 2; ++jt)
#pragma unroll
      for (int r = 0; r < 4; ++r) p[it][jt][r] *= inv;
  }
#pragma unroll
  for (int it = 0; it < 2; ++it)
#pragma unroll
    for (int jt = 0; jt < 2; ++jt) {
      unsigned int w0 =
          (unsigned int)f2bs(p[it][jt][0]) | ((unsigned int)f2bs(p[it][jt][1]) << 16);
      unsigned int w1 =
          (unsigned int)f2bs(p[it][jt][2]) | ((unsigned int)f2bs(p[it][jt][3]) << 16);
      uint2 pk = {w0, w1};
      *(uint2*)&Pl[wid][it * 16 + c][jt * 16 + 4 * q] = pk;
    }

  s16x8 pa[2];
#pragma unroll
  for (int it = 0; it < 2; ++it) pa[it] = *(const s16x8*)&Pl[wid][it * 16 + c][oct];
  f32x4 o[2][4];
#pragma unroll
  for (int it = 0; it < 2; ++it)
#pragma unroll
    for (int dt = 0; dt < 4; ++dt) {
      s16x8 vb = *(const s16x8*)&Vt[wid][dt * 16 + c][oct];
      f32x4 z = {0.f, 0.f, 0.f, 0.f};
      o[it][dt] = __builtin_amdgcn_mfma_f32_16x16x32_bf16(pa[it], vb, z, 0, 0, 0);
    }
#pragma unroll
  for (int it = 0; it < 2; ++it)
#pragma unroll
    for (int r = 0; r < 4; ++r) {
      int i = it * 16 + 4 * q + r;
      if (i < NTOK) {
        size_t rowoff = ((size_t)b * NTOK + i) * DIM + h * DHEAD;
#pragma unroll
        for (int dt = 0; dt < 4; ++dt) ao[rowoff + dt * 16 + c] = f2bs(o[it][dt][r]);
      }
    }
}

// ---------------- launcher ----------------
extern "C" void kernel_launch(void* const* d_in, const int* in_sizes, int n_in,
                              void* d_out, int out_size, void* d_ws, size_t ws_size,
                              hipStream_t stream) {
  (void)in_sizes; (void)n_in; (void)out_size; (void)ws_size;
  const float* x = (const float*)d_in[0];
  const float* ln1_g = (const float*)d_in[1];
  const float* ln1_b = (const float*)d_in[2];
  const float* w_qkv = (const float*)d_in[3];
  const float* scale = (const float*)d_in[4];
  const float* w_o = (const float*)d_in[5];
  const float* b_o = (const float*)d_in[6];
  const float* ln2_g = (const float*)d_in[7];
  const float* ln2_b = (const float*)d_in[8];
  const float* w1 = (const float*)d_in[9];
  const float* b1 = (const float*)d_in[10];
  const float* w2 = (const float*)d_in[11];
  const float* b2 = (const float*)d_in[12];

  char* ws = (char*)d_ws;
  unsigned short* buf1 = (unsigned short*)(ws + 0);
  unsigned short* qkv_bf = (unsigned short*)(ws + 24379392);
  unsigned short* x2 = (unsigned short*)(ws + 24379392);  // aliases qkv (qkv dead)
  unsigned short* g_bf = (unsigned short*)(ws + 97517568);
  unsigned short* wqkvT = (unsigned short*)(ws + 195035136);  // [2304][768]
  unsigned short* woT = (unsigned short*)(ws + 198574080);    // [768][768]
  unsigned short* w1T = (unsigned short*)(ws + 199753728);    // [3072][768]
  unsigned short* w2T = (unsigned short*)(ws + 204472320);    // [768][3072]

  transpose_all_kernel<<<1728, 256, 0, stream>>>(w_qkv, w_o, w1, w2, wqkvT, woT, w1T, w2T);

  ln_kernel<<<MTOK / 4, 256, 0, stream>>>(x, ln1_g, ln1_b, buf1);
  // qkv GEMM   [128x256 merged-phase, grid 1116 = 124 x 9, 2 blocks/CU]
  gemm_qkv<<<(MTOK / 128) * (QKVN / 256), 512, 0, stream>>>(
      buf1, wqkvT, qkv_bf, nullptr, nullptr, MTOK, QKVN, DIM, QKVN / 256);
  attn_mfma_kernel<<<(BATCH * HEADS) / 4, 256, 0, stream>>>(qkv_bf, scale, buf1);
  // proj + residual(x, f32) -> x2 (bf16)   [256x192 tiles, grid 248]
  gemm_proj<<<(MTOK / 256) * (DIM / 192), 512, 0, stream>>>(
      buf1, woT, x2, b_o, x, MTOK, DIM, DIM, DIM / 192);
  ln_bf16_kernel<<<MTOK / 4, 256, 0, stream>>>(x2, ln2_g, ln2_b, buf1);
  // mlp1 + tanh-GELU   [128x256 merged-phase, grid 1488 = 124 x 12, 2 blocks/CU]
  gemm_mlp1<<<(MTOK / 128) * (HIDDEN / 256), 512, 0, stream>>>(
      buf1, w1T, g_bf, b1, nullptr, MTOK, HIDDEN, DIM, HIDDEN / 256);
  // mlp2 + residual(x2, bf16) -> out (f32)   [256x192 tiles, grid 248]
  gemm_mlp2<<<(MTOK / 256) * (DIM / 192), 512, 0, stream>>>(
      g_bf, w2T, (float*)d_out, b2, x2, MTOK, DIM, HIDDEN, DIM / 192);
}

// Round 13
// 320.832 us; speedup vs baseline: 1.0090x; 1.0090x over previous
//
#include <hip/hip_runtime.h>
#include <math.h>

#define DIM 768
#define HEADS 12
#define DHEAD 64
#define NTOK 31
#define BATCH 512
#define MTOK (BATCH * NTOK)   /* 15872 */
#define HIDDEN 3072
#define QKVN 2304
#define MASK_VAL -987654321.0f

typedef short s16x8 __attribute__((ext_vector_type(8)));
typedef float f32x4 __attribute__((ext_vector_type(4)));

static __device__ __forceinline__ float bs2f(unsigned short u) {
  unsigned int x = ((unsigned int)u) << 16;
  return __builtin_bit_cast(float, x);
}
static __device__ __forceinline__ unsigned short f2bs(float f) {
  unsigned int x = __builtin_bit_cast(unsigned int, f);
  x += 0x7fffu + ((x >> 16) & 1u);
  return (unsigned short)(x >> 16);
}

// async global->LDS, 16B per lane, wave-uniform LDS base + lane*16
static __device__ __forceinline__ void gload16(const unsigned short* g, unsigned short* l) {
  __builtin_amdgcn_global_load_lds(
      (const __attribute__((address_space(1))) unsigned int*)g,
      (__attribute__((address_space(3))) unsigned int*)l, 16, 0, 0);
}

// pinned global->VGPR 16B load (position fixed by volatile; waits provided by the
// manual vmcnt ledger, NOT by the compiler -> rule #18 sched_barrier at use site)
static __device__ __forceinline__ s16x8 gload_reg(const char* p) {
  s16x8 r;
  asm volatile("global_load_dwordx4 %0, %1, off" : "=v"(r) : "v"(p));
  return r;
}

static __device__ __forceinline__ float epi_apply(int EPI, float v, int col, size_t idx,
                                                  const float* bias, const void* resid) {
  if (EPI == 0) return v;
  if (EPI == 2) {
    float t = v + bias[col];
    float arg = 1.5957691216f * t * (1.f + 0.044715f * t * t);
    return t * __builtin_amdgcn_rcpf(1.f + __expf(-arg));
  }
  if (EPI == 3) return v + bias[col] + ((const float*)resid)[idx];
  return v + bias[col] + bs2f(((const unsigned short*)resid)[idx]);  // EPI==4
}

static __device__ __forceinline__ void epi_store(int EPI, void* outp, size_t idx, float t) {
  if (EPI == 4) ((float*)outp)[idx] = t;
  else ((unsigned short*)outp)[idx] = f2bs(t);
}

// ---------------- batched weight transposes ----------------
// wqkvT, w1T -> fragment-native tiled layout: short-index
//   ((n>>4)*(K>>3) + (k>>3))*128 + (n&15)*8 + (k&7)
// woT, w2T -> flat [N][K] (gemm192 path unchanged)
__global__ __launch_bounds__(256) void transpose_all_kernel(
    const float* __restrict__ w_qkv, const float* __restrict__ w_o,
    const float* __restrict__ w1, const float* __restrict__ w2,
    unsigned short* __restrict__ wqkvT, unsigned short* __restrict__ woT,
    unsigned short* __restrict__ w1T, unsigned short* __restrict__ w2T) {
  int t = blockIdx.x;
  const float* w;
  unsigned short* wt;
  int K, N, tx, tiled;
  if (t < 432) { w = w_qkv; wt = wqkvT; K = DIM; N = QKVN; tx = QKVN / 64; tiled = 1; }
  else if (t < 576) { t -= 432; w = w_o; wt = woT; K = DIM; N = DIM; tx = DIM / 64; tiled = 0; }
  else if (t < 1152) { t -= 576; w = w1; wt = w1T; K = DIM; N = HIDDEN; tx = HIDDEN / 64; tiled = 1; }
  else { t -= 1152; w = w2; wt = w2T; K = HIDDEN; N = DIM; tx = DIM / 64; tiled = 0; }
  int n0 = (t % tx) * 64, k0 = (t / tx) * 64;

  __shared__ float tl[64][65];
  int tid = threadIdx.x;
  int r = tid >> 4, c4 = (tid & 15) * 4;
#pragma unroll
  for (int i = 0; i < 4; ++i) {
    float4 v = *(const float4*)(w + (size_t)(k0 + r + i * 16) * N + n0 + c4);
    tl[r + i * 16][c4] = v.x;
    tl[r + i * 16][c4 + 1] = v.y;
    tl[r + i * 16][c4 + 2] = v.z;
    tl[r + i * 16][c4 + 3] = v.w;
  }
  __syncthreads();
#pragma unroll
  for (int i = 0; i < 4; ++i) {
    int n = r + i * 16;
    ushort4 o;
    o.x = f2bs(tl[c4 + 0][n]);
    o.y = f2bs(tl[c4 + 1][n]);
    o.z = f2bs(tl[c4 + 2][n]);
    o.w = f2bs(tl[c4 + 3][n]);
    if (tiled) {
      size_t si = ((size_t)((n0 + n) >> 4) * (K >> 3) + ((k0 + c4) >> 3)) * 128 +
                  (n & 15) * 8 + (c4 & 7);
      *(ushort4*)(wt + si) = o;
    } else {
      *(ushort4*)(wt + (size_t)(n0 + n) * K + k0 + c4) = o;
    }
  }
}

// ---------------- LayerNorm (f32 in) ----------------
__global__ __launch_bounds__(256) void ln_kernel(const float* __restrict__ x,
                                                 const float* __restrict__ g,
                                                 const float* __restrict__ bta,
                                                 unsigned short* __restrict__ out) {
  int wid = threadIdx.x >> 6, lane = threadIdx.x & 63;
  size_t row = (size_t)blockIdx.x * 4 + wid;
  const float4* xr = (const float4*)(x + row * DIM);
  float4 v[3];
  v[0] = xr[lane];
  v[1] = xr[lane + 64];
  v[2] = xr[lane + 128];
  float s = 0.f, sq = 0.f;
#pragma unroll
  for (int i = 0; i < 3; ++i) {
    s += v[i].x + v[i].y + v[i].z + v[i].w;
    sq += v[i].x * v[i].x + v[i].y * v[i].y + v[i].z * v[i].z + v[i].w * v[i].w;
  }
#pragma unroll
  for (int off = 32; off; off >>= 1) {
    s += __shfl_xor(s, off);
    sq += __shfl_xor(sq, off);
  }
  float mu = s * (1.f / DIM);
  float var = sq * (1.f / DIM) - mu * mu;
  float rs = rsqrtf(var + 1e-5f);
#pragma unroll
  for (int i = 0; i < 3; ++i) {
    int col = i * 256 + lane * 4;
    float4 gg = *(const float4*)(g + col);
    float4 bb = *(const float4*)(bta + col);
    ushort4 o;
    o.x = f2bs((v[i].x - mu) * rs * gg.x + bb.x);
    o.y = f2bs((v[i].y - mu) * rs * gg.y + bb.y);
    o.z = f2bs((v[i].z - mu) * rs * gg.z + bb.z);
    o.w = f2bs((v[i].w - mu) * rs * gg.w + bb.w);
    *(ushort4*)(out + row * DIM + col) = o;
  }
}

// ---------------- LayerNorm (bf16 in) ----------------
__global__ __launch_bounds__(256) void ln_bf16_kernel(const unsigned short* __restrict__ x,
                                                      const float* __restrict__ g,
                                                      const float* __restrict__ bta,
                                                      unsigned short* __restrict__ out) {
  int wid = threadIdx.x >> 6, lane = threadIdx.x & 63;
  size_t row = (size_t)blockIdx.x * 4 + wid;
  const unsigned short* xr = x + row * DIM;
  float v[12];
#pragma unroll
  for (int i = 0; i < 3; ++i) {
    ushort4 u = *(const ushort4*)(xr + i * 256 + lane * 4);
    v[i * 4 + 0] = bs2f(u.x);
    v[i * 4 + 1] = bs2f(u.y);
    v[i * 4 + 2] = bs2f(u.z);
    v[i * 4 + 3] = bs2f(u.w);
  }
  float s = 0.f, sq = 0.f;
#pragma unroll
  for (int i = 0; i < 12; ++i) {
    s += v[i];
    sq += v[i] * v[i];
  }
#pragma unroll
  for (int off = 32; off; off >>= 1) {
    s += __shfl_xor(s, off);
    sq += __shfl_xor(sq, off);
  }
  float mu = s * (1.f / DIM);
  float var = sq * (1.f / DIM) - mu * mu;
  float rs = rsqrtf(var + 1e-5f);
#pragma unroll
  for (int i = 0; i < 3; ++i) {
    int col = i * 256 + lane * 4;
    float4 gg = *(const float4*)(g + col);
    float4 bb = *(const float4*)(bta + col);
    ushort4 o;
    o.x = f2bs((v[i * 4 + 0] - mu) * rs * gg.x + bb.x);
    o.y = f2bs((v[i * 4 + 1] - mu) * rs * gg.y + bb.y);
    o.z = f2bs((v[i * 4 + 2] - mu) * rs * gg.z + bb.z);
    o.w = f2bs((v[i * 4 + 3] - mu) * rs * gg.w + bb.w);
    *(ushort4*)(out + row * DIM + col) = o;
  }
}

// ================= B-direct 128x256 BK=32 GEMM (qkv, mlp1; K==768, NT=24) =================
// A via LDS (3-deep, 8KB/buf, 4x wave reuse); B direct global->VGPR from tiled
// layout, double-buffered in regs, loaded for p+2 after phase p's MFMA.
// Phase p: [stgA(p+2)] [4 ds_read A] [vmcnt(V)] [barrier] [lgkm0] [sched_barrier]
//          [16 MFMA w/ bk[p&1]] [4 B-loads -> bk[p&1] for p+2] [barrier]
// Ledger (A=1 op, B=4 ops; issue order per phase: A(p+2) then B(p+2)):
//   prologue A0,A1,B0x4,B1x4 -> vmcnt(8) retires A0(,A1).
//   steady p<=21: vmcnt(5) retires ...B(p)x4,A(p+1); leaves B(p+1)x4+A(p+2).
//   p22: queue B22x4,A23,B23x4 -> vmcnt(4) retires B22,A23. p23: vmcnt(0).
template <int ABUF, int BSEL, int VM, typename SA, typename SB>
__device__ __forceinline__ void gphd(const char* aBase, s16x8 (&bk)[2][4],
                                     f32x4 (&acc)[4][4], SA&& stageA, SB&& loadB) {
  stageA();
  s16x8 af[4];
#pragma unroll
  for (int mi = 0; mi < 4; ++mi)
    af[mi] = *(const s16x8*)(aBase + ABUF * 8192 + mi * 1024);
  if (VM == 5) asm volatile("s_waitcnt vmcnt(5)");
  if (VM == 4) asm volatile("s_waitcnt vmcnt(4)");
  if (VM == 0) asm volatile("s_waitcnt vmcnt(0)");
  __builtin_amdgcn_s_barrier();
  asm volatile("s_waitcnt lgkmcnt(0)");
  __builtin_amdgcn_sched_barrier(0);
  __builtin_amdgcn_s_setprio(1);
#pragma unroll
  for (int mi = 0; mi < 4; ++mi)
#pragma unroll
    for (int ni = 0; ni < 4; ++ni)
      acc[mi][ni] =
          __builtin_amdgcn_mfma_f32_16x16x32_bf16(af[mi], bk[BSEL][ni], acc[mi][ni], 0, 0, 0);
  __builtin_amdgcn_s_setprio(0);
  loadB();
  __builtin_amdgcn_s_barrier();
}

template <int EPI>
__device__ __forceinline__ void gemm128d_body(
    const unsigned short* __restrict__ A, const unsigned short* __restrict__ Bt,
    void* __restrict__ outp, const float* __restrict__ bias,
    const void* __restrict__ resid, int M, int N, int ntn) {
  constexpr int K = 768;  // NT = 24
  __shared__ char ldsc[24576];  // A only: 3 x 8KB
  int tid = threadIdx.x;
  int lane = tid & 63, w = tid >> 6;
  int wm = w >> 2, wn = w & 3;
  int fr = lane & 15, q = lane >> 4;

  int nwg = gridDim.x, orig = blockIdx.x;
  int qd = nwg >> 3, r8 = nwg & 7, xcd = orig & 7, loc = orig >> 3;
  int bid = (xcd < r8 ? xcd * (qd + 1) : r8 * (qd + 1) + (xcd - r8) * qd) + loc;
  int m0 = (bid / ntn) * 128, n0 = (bid % ntn) * 256;

  int rdoff = (q * 16) ^ (((fr >> 1) & 3) << 4);
  const char* aBase = ldsc + (wm * 64 + fr) * 64 + rdoff;

  int srow = tid >> 2;  // 0..127
  int seoff = (((tid & 3) ^ ((srow >> 1) & 3))) << 3;
  const char* Ab = (const char*)A + ((size_t)(m0 + srow) * K + seoff) * 2;

  // B tiled-layout per-lane bases: addr(ni, p) = bB[ni] + p*1024
  const char* bB[4];
#pragma unroll
  for (int ni = 0; ni < 4; ++ni)
    bB[ni] = (const char*)Bt +
             ((size_t)((n0 + wn * 64 + ni * 16) >> 4) * (K >> 3) + q) * 256 + fr * 16;

  auto stgA = [&](int buf, int tile) {
    gload16((const unsigned short*)(Ab + tile * 64),
            (unsigned short*)(ldsc + buf * 8192 + w * 1024));
  };
  s16x8 bk[2][4];
  auto loadB = [&](int sel, int tile) {
#pragma unroll
    for (int ni = 0; ni < 4; ++ni) bk[sel][ni] = gload_reg(bB[ni] + (size_t)tile * 1024);
  };

  f32x4 acc[4][4] = {};

  // prologue: A0, A1, B0, B1 -> vmcnt(8) (retires A0,A1)
  stgA(0, 0);
  stgA(1, 1);
  loadB(0, 0);
  loadB(1, 1);
  asm volatile("s_waitcnt vmcnt(8)");
  __builtin_amdgcn_s_barrier();

#define PH(p) gphd<(p) % 3, (p) & 1, 5>(aBase, bk, acc, \
      [&] { stgA(((p) + 2) % 3, (p) + 2); }, [&] { loadB((p) & 1, (p) + 2); })
  PH(0); PH(1); PH(2); PH(3); PH(4); PH(5);
  PH(6); PH(7); PH(8); PH(9); PH(10); PH(11);
  PH(12); PH(13); PH(14); PH(15); PH(16); PH(17);
  PH(18); PH(19); PH(20); PH(21);
#undef PH
  auto nopA = [&] {};
  auto nopB = [&] {};
  gphd<22 % 3, 0, 4>(aBase, bk, acc, nopA, nopB);
  gphd<23 % 3, 1, 0>(aBase, bk, acc, nopA, nopB);

#pragma unroll
  for (int am = 0; am < 4; ++am)
#pragma unroll
    for (int ni = 0; ni < 4; ++ni)
#pragma unroll
      for (int rr = 0; rr < 4; ++rr) {
        int row = m0 + wm * 64 + am * 16 + q * 4 + rr;
        int col = n0 + wn * 64 + ni * 16 + fr;
        size_t idx = (size_t)row * N + col;
        epi_store(EPI, outp, idx, epi_apply(EPI, acc[am][ni][rr], col, idx, bias, resid));
      }
}

// ================= 8-phase 256x192 GEMM (fill path: proj, mlp2) =================
template <int BUF, int MH, int KH, int VM, typename STF>
__device__ __forceinline__ void gph192(const char* aB0, const char* bKH0, const char* bKH1,
                                       s16x8 (&bk)[3], f32x4 (&acc)[8][3], STF&& stage) {
  const char* aP = aB0 + BUF * 32768 + KH * 16384 + MH * 4096;
  s16x8 af[4];
  if (MH == 0) {
    const char* bp = (KH ? bKH1 : bKH0) + BUF * 24576;
#pragma unroll
    for (int ni = 0; ni < 3; ++ni) bk[ni] = *(const s16x8*)(bp + ni * 2048);
  }
#pragma unroll
  for (int mi = 0; mi < 4; ++mi) af[mi] = *(const s16x8*)(aP + mi * 1024);
  stage();
  if (VM == 2) asm volatile("s_waitcnt vmcnt(2)");
  if (VM == 0) asm volatile("s_waitcnt vmcnt(0)");
  __builtin_amdgcn_s_barrier();
  asm volatile("s_waitcnt lgkmcnt(0)");
  __builtin_amdgcn_s_setprio(1);
#pragma unroll
  for (int mi = 0; mi < 4; ++mi)
#pragma unroll
    for (int ni = 0; ni < 3; ++ni)
      acc[MH * 4 + mi][ni] =
          __builtin_amdgcn_mfma_f32_16x16x32_bf16(af[mi], bk[ni], acc[MH * 4 + mi][ni], 0, 0, 0);
  __builtin_amdgcn_s_setprio(0);
  __builtin_amdgcn_s_barrier();
}

template <int EPI>
__device__ __forceinline__ void gemm192_body(
    const unsigned short* __restrict__ A, const unsigned short* __restrict__ Bt,
    void* __restrict__ outp, const float* __restrict__ bias,
    const void* __restrict__ resid, int M, int N, int K, int ntn) {
  __shared__ char ldsc[114688];  // 112 KiB
  int tid = threadIdx.x;
  int lane = tid & 63, w = tid >> 6;
  int wm = w >> 2, wn = w & 3;
  int fr = lane & 15, q = lane >> 4;

  int nwg = gridDim.x, orig = blockIdx.x;
  int qd = nwg >> 3, r8 = nwg & 7, xcd = orig & 7, loc = orig >> 3;
  int bid = (xcd < r8 ? xcd * (qd + 1) : r8 * (qd + 1) + (xcd - r8) * qd) + loc;
  int m0 = (bid / ntn) * 256, n0 = (bid % ntn) * 192;

  int rdoffA = (q * 16) ^ (((fr >> 1) & 3) << 4);
  const char* aB0 = ldsc + (wm * 128 + fr) * 64 + rdoffA;
  int brow0 = wn * 48 + fr;
  int bsw = brow0 & 7;
  const char* bBase = ldsc + 65536 + brow0 * 128 + (q ^ (bsw & 3)) * 16;
  const char* bKH0 = bBase + ((0 ^ (bsw >> 2)) * 64);
  const char* bKH1 = bBase + ((1 ^ (bsw >> 2)) * 64);

  int srow = tid >> 2;
  int seoffA = (((tid & 3) ^ ((srow >> 1) & 3))) << 3;
  const char* Ab = (const char*)A + ((size_t)(m0 + srow) * K + seoffA) * 2;
  size_t rstep = (size_t)K * 256;
  auto stgA = [&](int kh, int buf, int tile) {
    const char* gp = Ab + tile * 128 + kh * 64;
    unsigned short* lp = (unsigned short*)(ldsc + buf * 32768 + kh * 16384 + w * 1024);
    gload16((const unsigned short*)gp, lp);
    gload16((const unsigned short*)(gp + rstep), (unsigned short*)((char*)lp + 8192));
  };
  const char* Bb2 = (const char*)Bt +
                    ((size_t)(n0 + (tid >> 3)) * K + (((tid & 7) ^ ((tid >> 3) & 7)) * 8)) * 2;
  auto stgB = [&](int j, int buf, int tile) {
    gload16((const unsigned short*)(Bb2 + (size_t)j * 128 * K + tile * 128),
            (unsigned short*)(ldsc + 65536 + buf * 24576 + j * 8192 + w * 1024));
  };
  auto nop = [&] {};

  f32x4 acc[8][3] = {};
  s16x8 bk[3];
  int NT = K / 64;

  stgA(0, 0, 0);
  stgA(1, 0, 0);
  stgB(0, 0, 0);
  stgB(1, 0, 0);
  stgB(2, 0, 0);
  stgA(0, 1, 1);
  asm volatile("s_waitcnt vmcnt(2)");
  __builtin_amdgcn_s_barrier();

  for (int t = 0; t + 3 < NT; t += 2) {
    gph192<0, 0, 0, -1>(aB0, bKH0, bKH1, bk, acc,
                        [&] { stgA(1, 1, t + 1); stgB(0, 1, t + 1); stgB(1, 1, t + 1); });
    gph192<0, 1, 0, -1>(aB0, bKH0, bKH1, bk, acc, [&] { stgB(2, 1, t + 1); });
    gph192<0, 0, 1, -1>(aB0, bKH0, bKH1, bk, acc, [&] { stgA(0, 0, t + 2); });
    gph192<0, 1, 1, 2>(aB0, bKH0, bKH1, bk, acc, nop);
    gph192<1, 0, 0, -1>(aB0, bKH0, bKH1, bk, acc,
                        [&] { stgA(1, 0, t + 2); stgB(0, 0, t + 2); stgB(1, 0, t + 2); });
    gph192<1, 1, 0, -1>(aB0, bKH0, bKH1, bk, acc, [&] { stgB(2, 0, t + 2); });
    gph192<1, 0, 1, -1>(aB0, bKH0, bKH1, bk, acc, [&] { stgA(0, 1, t + 3); });
    gph192<1, 1, 1, 2>(aB0, bKH0, bKH1, bk, acc, nop);
  }
  gph192<0, 0, 0, -1>(aB0, bKH0, bKH1, bk, acc,
                      [&] { stgA(1, 1, NT - 1); stgB(0, 1, NT - 1); stgB(1, 1, NT - 1); });
  gph192<0, 1, 0, -1>(aB0, bKH0, bKH1, bk, acc, [&] { stgB(2, 1, NT - 1); });
  gph192<0, 0, 1, -1>(aB0, bKH0, bKH1, bk, acc, nop);
  gph192<0, 1, 1, 0>(aB0, bKH0, bKH1, bk, acc, nop);
  gph192<1, 0, 0, -1>(aB0, bKH0, bKH1, bk, acc, nop);
  gph192<1, 1, 0, -1>(aB0, bKH0, bKH1, bk, acc, nop);
  gph192<1, 0, 1, -1>(aB0, bKH0, bKH1, bk, acc, nop);
  gph192<1, 1, 1, -1>(aB0, bKH0, bKH1, bk, acc, nop);

#pragma unroll
  for (int am = 0; am < 8; ++am)
#pragma unroll
    for (int ni = 0; ni < 3; ++ni)
#pragma unroll
      for (int rr = 0; rr < 4; ++rr) {
        int row = m0 + wm * 128 + am * 16 + q * 4 + rr;
        int col = n0 + wn * 48 + ni * 16 + fr;
        size_t idx = (size_t)row * N + col;
        epi_store(EPI, outp, idx, epi_apply(EPI, acc[am][ni][rr], col, idx, bias, resid));
      }
}

// named wrappers for rocprof attribution
__global__ __launch_bounds__(512, 2) void gemm_qkv(const unsigned short* A,
                                                   const unsigned short* Bt, void* o,
                                                   const float* b, const void* r, int M,
                                                   int N, int ntn) {
  gemm128d_body<0>(A, Bt, o, b, r, M, N, ntn);
}
__global__ __launch_bounds__(512, 2) void gemm_mlp1(const unsigned short* A,
                                                    const unsigned short* Bt, void* o,
                                                    const float* b, const void* r, int M,
                                                    int N, int ntn) {
  gemm128d_body<2>(A, Bt, o, b, r, M, N, ntn);
}
__global__ __launch_bounds__(512, 2) void gemm_proj(const unsigned short* A,
                                                    const unsigned short* Bt, void* o,
                                                    const float* b, const void* r, int M,
                                                    int N, int K, int ntn) {
  gemm192_body<3>(A, Bt, o, b, r, M, N, K, ntn);
}
__global__ __launch_bounds__(512, 2) void gemm_mlp2(const unsigned short* A,
                                                    const unsigned short* Bt, void* o,
                                                    const float* b, const void* r, int M,
                                                    int N, int K, int ntn) {
  gemm192_body<4>(A, Bt, o, b, r, M, N, K, ntn);
}

// ---------------- MFMA attention: one wave per (batch, head) ----------------
__global__ __launch_bounds__(256) void attn_mfma_kernel(const unsigned short* __restrict__ qkv,
                                                        const float* __restrict__ scale,
                                                        unsigned short* __restrict__ ao) {
  __shared__ unsigned short Vt[4][64][40];
  __shared__ unsigned short Pl[4][32][32];
  int wid = threadIdx.x >> 6, lane = threadIdx.x & 63;
  int pair = blockIdx.x * 4 + wid;
  int b = pair / HEADS, h = pair % HEADS;
  const unsigned short* base = qkv + (size_t)b * NTOK * QKVN + h * DHEAD;
  const unsigned short* Qp = base;
  const unsigned short* Kp = base + 768;
  const unsigned short* Vp = base + 1536;

  int c = lane & 15, q = lane >> 4;
  int oct = q * 8;

  unsigned short vcol[NTOK];
#pragma unroll
  for (int j = 0; j < NTOK; ++j) vcol[j] = Vp[(size_t)j * QKVN + lane];
#pragma unroll
  for (int j = 0; j < NTOK; ++j) Vt[wid][lane][j] = vcol[j];
  Vt[wid][lane][31] = 0;

  s16x8 kf[2][2] = {{{0}}}, qf[2][2] = {{{0}}};
#pragma unroll
  for (int t = 0; t < 2; ++t) {
    int row = t * 16 + c;
    if (row < NTOK) {
#pragma unroll
      for (int s = 0; s < 2; ++s) {
        kf[t][s] = *(const s16x8*)(Kp + (size_t)row * QKVN + s * 32 + oct);
        qf[t][s] = *(const s16x8*)(Qp + (size_t)row * QKVN + s * 32 + oct);
      }
    }
  }

  f32x4 st[2][2] = {};
#pragma unroll
  for (int jt = 0; jt < 2; ++jt)
#pragma unroll
    for (int it = 0; it < 2; ++it)
#pragma unroll
      for (int s = 0; s < 2; ++s)
        st[jt][it] =
            __builtin_amdgcn_mfma_f32_16x16x32_bf16(kf[jt][s], qf[it][s], st[jt][it], 0, 0, 0);

  float scl = scale[h];
  float p[2][2][4];
#pragma unroll
  for (int it = 0; it < 2; ++it)
#pragma unroll
    for (int jt = 0; jt < 2; ++jt)
#pragma unroll
      for (int r = 0; r < 4; ++r) {
        int j = jt * 16 + 4 * q + r;
        int i = it * 16 + c;
        float v = st[jt][it][r] * scl;
        if (j == 31 || j == i) v = MASK_VAL;
        p[it][jt][r] = v;
      }
#pragma unroll
  for (int it = 0; it < 2; ++it) {
    float m = p[it][0][0];
#pragma unroll
    for (int jt = 0; jt < 2; ++jt)
#pragma unroll
      for (int r = 0; r < 4; ++r) m = fmaxf(m, p[it][jt][r]);
    m = fmaxf(m, __shfl_xor(m, 16));
    m = fmaxf(m, __shfl_xor(m, 32));
    float s = 0.f;
#pragma unroll
    for (int jt = 0; jt < 2; ++jt)
#pragma unroll
      for (int r = 0; r < 4; ++r) {
        float e = __expf(p[it][jt][r] - m);
        p[it][jt][r] = e;
        s += e;
      }
    s += __shfl_xor(s, 16);
    s += __shfl_xor(s, 32);
    float inv = __builtin_amdgcn_rcpf(s);
#pragma unroll
    for (int jt = 0; jt < 2; ++jt)
#pragma unroll
      for (int r = 0; r < 4; ++r) p[it][jt][r] *= inv;
  }
#pragma unroll
  for (int it = 0; it < 2; ++it)
#pragma unroll
    for (int jt = 0; jt < 2; ++jt) {
      unsigned int w0 =
          (unsigned int)f2bs(p[it][jt][0]) | ((unsigned int)f2bs(p[it][jt][1]) << 16);
      unsigned int w1 =
          (unsigned int)f2bs(p[it][jt][2]) | ((unsigned int)f2bs(p[it][jt][3]) << 16);
      uint2 pk = {w0, w1};
      *(uint2*)&Pl[wid][it * 16 + c][jt * 16 + 4 * q] = pk;
    }

  s16x8 pa[2];
#pragma unroll
  for (int it = 0; it < 2; ++it) pa[it] = *(const s16x8*)&Pl[wid][it * 16 + c][oct];
  f32x4 o[2][4];
#pragma unroll
  for (int it = 0; it < 2; ++it)
#pragma unroll
    for (int dt = 0; dt < 4; ++dt) {
      s16x8 vb = *(const s16x8*)&Vt[wid][dt * 16 + c][oct];
      f32x4 z = {0.f, 0.f, 0.f, 0.f};
      o[it][dt] = __builtin_amdgcn_mfma_f32_16x16x32_bf16(pa[it], vb, z, 0, 0, 0);
    }
#pragma unroll
  for (int it = 0; it < 2; ++it)
#pragma unroll
    for (int r = 0; r < 4; ++r) {
      int i = it * 16 + 4 * q + r;
      if (i < NTOK) {
        size_t rowoff = ((size_t)b * NTOK + i) * DIM + h * DHEAD;
#pragma unroll
        for (int dt = 0; dt < 4; ++dt) ao[rowoff + dt * 16 + c] = f2bs(o[it][dt][r]);
      }
    }
}

// ---------------- launcher ----------------
extern "C" void kernel_launch(void* const* d_in, const int* in_sizes, int n_in,
                              void* d_out, int out_size, void* d_ws, size_t ws_size,
                              hipStream_t stream) {
  (void)in_sizes; (void)n_in; (void)out_size; (void)ws_size;
  const float* x = (const float*)d_in[0];
  const float* ln1_g = (const float*)d_in[1];
  const float* ln1_b = (const float*)d_in[2];
  const float* w_qkv = (const float*)d_in[3];
  const float* scale = (const float*)d_in[4];
  const float* w_o = (const float*)d_in[5];
  const float* b_o = (const float*)d_in[6];
  const float* ln2_g = (const float*)d_in[7];
  const float* ln2_b = (const float*)d_in[8];
  const float* w1 = (const float*)d_in[9];
  const float* b1 = (const float*)d_in[10];
  const float* w2 = (const float*)d_in[11];
  const float* b2 = (const float*)d_in[12];

  char* ws = (char*)d_ws;
  unsigned short* buf1 = (unsigned short*)(ws + 0);
  unsigned short* qkv_bf = (unsigned short*)(ws + 24379392);
  unsigned short* x2 = (unsigned short*)(ws + 24379392);  // aliases qkv (qkv dead)
  unsigned short* g_bf = (unsigned short*)(ws + 97517568);
  unsigned short* wqkvT = (unsigned short*)(ws + 195035136);  // tiled [2304][768]
  unsigned short* woT = (unsigned short*)(ws + 198574080);    // flat  [768][768]
  unsigned short* w1T = (unsigned short*)(ws + 199753728);    // tiled [3072][768]
  unsigned short* w2T = (unsigned short*)(ws + 204472320);    // flat  [768][3072]

  transpose_all_kernel<<<1728, 256, 0, stream>>>(w_qkv, w_o, w1, w2, wqkvT, woT, w1T, w2T);

  ln_kernel<<<MTOK / 4, 256, 0, stream>>>(x, ln1_g, ln1_b, buf1);
  // qkv GEMM   [128x256 B-direct, grid 1116 = 124 x 9]
  gemm_qkv<<<(MTOK / 128) * (QKVN / 256), 512, 0, stream>>>(
      buf1, wqkvT, qkv_bf, nullptr, nullptr, MTOK, QKVN, QKVN / 256);
  attn_mfma_kernel<<<(BATCH * HEADS) / 4, 256, 0, stream>>>(qkv_bf, scale, buf1);
  // proj + residual(x, f32) -> x2 (bf16)   [256x192 tiles, grid 248]
  gemm_proj<<<(MTOK / 256) * (DIM / 192), 512, 0, stream>>>(
      buf1, woT, x2, b_o, x, MTOK, DIM, DIM, DIM / 192);
  ln_bf16_kernel<<<MTOK / 4, 256, 0, stream>>>(x2, ln2_g, ln2_b, buf1);
  // mlp1 + tanh-GELU   [128x256 B-direct, grid 1488 = 124 x 12]
  gemm_mlp1<<<(MTOK / 128) * (HIDDEN / 256), 512, 0, stream>>>(
      buf1, w1T, g_bf, b1, nullptr, MTOK, HIDDEN, HIDDEN / 256);
  // mlp2 + residual(x2, bf16) -> out (f32)   [256x192 tiles, grid 248]
  gemm_mlp2<<<(MTOK / 256) * (DIM / 192), 512, 0, stream>>>(
      g_bf, w2T, (float*)d_out, b2, x2, MTOK, DIM, HIDDEN, DIM / 192);
}

// Round 14
// 313.206 us; speedup vs baseline: 1.0335x; 1.0243x over previous
//
#include <hip/hip_runtime.h>
#include <math.h>

#define DIM 768
#define HEADS 12
#define DHEAD 64
#define NTOK 31
#define BATCH 512
#define MTOK (BATCH * NTOK)   /* 15872 */
#define HIDDEN 3072
#define QKVN 2304
#define MASK_VAL -987654321.0f

typedef short s16x8 __attribute__((ext_vector_type(8)));
typedef float f32x4 __attribute__((ext_vector_type(4)));

static __device__ __forceinline__ float bs2f(unsigned short u) {
  unsigned int x = ((unsigned int)u) << 16;
  return __builtin_bit_cast(float, x);
}
static __device__ __forceinline__ unsigned short f2bs(float f) {
  unsigned int x = __builtin_bit_cast(unsigned int, f);
  x += 0x7fffu + ((x >> 16) & 1u);
  return (unsigned short)(x >> 16);
}

// async global->LDS, 16B per lane, wave-uniform LDS base + lane*16
static __device__ __forceinline__ void gload16(const unsigned short* g, unsigned short* l) {
  __builtin_amdgcn_global_load_lds(
      (const __attribute__((address_space(1))) unsigned int*)g,
      (__attribute__((address_space(3))) unsigned int*)l, 16, 0, 0);
}

static __device__ __forceinline__ float epi_apply(int EPI, float v, int col, size_t idx,
                                                  const float* bias, const void* resid) {
  if (EPI == 0) return v;
  if (EPI == 2) {
    float t = v + bias[col];
    float arg = 1.5957691216f * t * (1.f + 0.044715f * t * t);
    return t * __builtin_amdgcn_rcpf(1.f + __expf(-arg));
  }
  if (EPI == 3) return v + bias[col] + ((const float*)resid)[idx];
  return v + bias[col] + bs2f(((const unsigned short*)resid)[idx]);  // EPI==4
}

static __device__ __forceinline__ void epi_store(int EPI, void* outp, size_t idx, float t) {
  if (EPI == 4) ((float*)outp)[idx] = t;
  else ((unsigned short*)outp)[idx] = f2bs(t);
}

// ---------------- batched weight transposes: all flat [N][K] bf16 ----------------
__global__ __launch_bounds__(256) void transpose_all_kernel(
    const float* __restrict__ w_qkv, const float* __restrict__ w_o,
    const float* __restrict__ w1, const float* __restrict__ w2,
    unsigned short* __restrict__ wqkvT, unsigned short* __restrict__ woT,
    unsigned short* __restrict__ w1T, unsigned short* __restrict__ w2T) {
  int t = blockIdx.x;
  const float* w;
  unsigned short* wt;
  int K, N, tx;
  if (t < 432) { w = w_qkv; wt = wqkvT; K = DIM; N = QKVN; tx = QKVN / 64; }
  else if (t < 576) { t -= 432; w = w_o; wt = woT; K = DIM; N = DIM; tx = DIM / 64; }
  else if (t < 1152) { t -= 576; w = w1; wt = w1T; K = DIM; N = HIDDEN; tx = HIDDEN / 64; }
  else { t -= 1152; w = w2; wt = w2T; K = HIDDEN; N = DIM; tx = DIM / 64; }
  int n0 = (t % tx) * 64, k0 = (t / tx) * 64;

  __shared__ float tl[64][65];
  int tid = threadIdx.x;
  int r = tid >> 4, c4 = (tid & 15) * 4;
#pragma unroll
  for (int i = 0; i < 4; ++i) {
    float4 v = *(const float4*)(w + (size_t)(k0 + r + i * 16) * N + n0 + c4);
    tl[r + i * 16][c4] = v.x;
    tl[r + i * 16][c4 + 1] = v.y;
    tl[r + i * 16][c4 + 2] = v.z;
    tl[r + i * 16][c4 + 3] = v.w;
  }
  __syncthreads();
#pragma unroll
  for (int i = 0; i < 4; ++i) {
    int n = r + i * 16;
    ushort4 o;
    o.x = f2bs(tl[c4 + 0][n]);
    o.y = f2bs(tl[c4 + 1][n]);
    o.z = f2bs(tl[c4 + 2][n]);
    o.w = f2bs(tl[c4 + 3][n]);
    *(ushort4*)(wt + (size_t)(n0 + n) * K + k0 + c4) = o;
  }
}

// ---------------- LayerNorm (f32 in) ----------------
__global__ __launch_bounds__(256) void ln_kernel(const float* __restrict__ x,
                                                 const float* __restrict__ g,
                                                 const float* __restrict__ bta,
                                                 unsigned short* __restrict__ out) {
  int wid = threadIdx.x >> 6, lane = threadIdx.x & 63;
  size_t row = (size_t)blockIdx.x * 4 + wid;
  const float4* xr = (const float4*)(x + row * DIM);
  float4 v[3];
  v[0] = xr[lane];
  v[1] = xr[lane + 64];
  v[2] = xr[lane + 128];
  float s = 0.f, sq = 0.f;
#pragma unroll
  for (int i = 0; i < 3; ++i) {
    s += v[i].x + v[i].y + v[i].z + v[i].w;
    sq += v[i].x * v[i].x + v[i].y * v[i].y + v[i].z * v[i].z + v[i].w * v[i].w;
  }
#pragma unroll
  for (int off = 32; off; off >>= 1) {
    s += __shfl_xor(s, off);
    sq += __shfl_xor(sq, off);
  }
  float mu = s * (1.f / DIM);
  float var = sq * (1.f / DIM) - mu * mu;
  float rs = rsqrtf(var + 1e-5f);
#pragma unroll
  for (int i = 0; i < 3; ++i) {
    int col = i * 256 + lane * 4;
    float4 gg = *(const float4*)(g + col);
    float4 bb = *(const float4*)(bta + col);
    ushort4 o;
    o.x = f2bs((v[i].x - mu) * rs * gg.x + bb.x);
    o.y = f2bs((v[i].y - mu) * rs * gg.y + bb.y);
    o.z = f2bs((v[i].z - mu) * rs * gg.z + bb.z);
    o.w = f2bs((v[i].w - mu) * rs * gg.w + bb.w);
    *(ushort4*)(out + row * DIM + col) = o;
  }
}

// ---------------- LayerNorm (bf16 in) ----------------
__global__ __launch_bounds__(256) void ln_bf16_kernel(const unsigned short* __restrict__ x,
                                                      const float* __restrict__ g,
                                                      const float* __restrict__ bta,
                                                      unsigned short* __restrict__ out) {
  int wid = threadIdx.x >> 6, lane = threadIdx.x & 63;
  size_t row = (size_t)blockIdx.x * 4 + wid;
  const unsigned short* xr = x + row * DIM;
  float v[12];
#pragma unroll
  for (int i = 0; i < 3; ++i) {
    ushort4 u = *(const ushort4*)(xr + i * 256 + lane * 4);
    v[i * 4 + 0] = bs2f(u.x);
    v[i * 4 + 1] = bs2f(u.y);
    v[i * 4 + 2] = bs2f(u.z);
    v[i * 4 + 3] = bs2f(u.w);
  }
  float s = 0.f, sq = 0.f;
#pragma unroll
  for (int i = 0; i < 12; ++i) {
    s += v[i];
    sq += v[i] * v[i];
  }
#pragma unroll
  for (int off = 32; off; off >>= 1) {
    s += __shfl_xor(s, off);
    sq += __shfl_xor(sq, off);
  }
  float mu = s * (1.f / DIM);
  float var = sq * (1.f / DIM) - mu * mu;
  float rs = rsqrtf(var + 1e-5f);
#pragma unroll
  for (int i = 0; i < 3; ++i) {
    int col = i * 256 + lane * 4;
    float4 gg = *(const float4*)(g + col);
    float4 bb = *(const float4*)(bta + col);
    ushort4 o;
    o.x = f2bs((v[i * 4 + 0] - mu) * rs * gg.x + bb.x);
    o.y = f2bs((v[i * 4 + 1] - mu) * rs * gg.y + bb.y);
    o.z = f2bs((v[i * 4 + 2] - mu) * rs * gg.z + bb.z);
    o.w = f2bs((v[i * 4 + 3] - mu) * rs * gg.w + bb.w);
    *(ushort4*)(out + row * DIM + col) = o;
  }
}

// ================= persistent 8-phase 256x192 GEMM (all four GEMMs) =================
// TPB tiles per block, consecutive tile ids (share m0 -> A-panel L2 reuse).
// Grid = total_tiles / TPB = 248 everywhere (248%8==0 -> clean XCD swizzle).
template <int BUF, int MH, int KH, int VM, typename STF>
__device__ __forceinline__ void gph192(const char* aB0, const char* bKH0, const char* bKH1,
                                       s16x8 (&bk)[3], f32x4 (&acc)[8][3], STF&& stage) {
  const char* aP = aB0 + BUF * 32768 + KH * 16384 + MH * 4096;
  s16x8 af[4];
  if (MH == 0) {
    const char* bp = (KH ? bKH1 : bKH0) + BUF * 24576;
#pragma unroll
    for (int ni = 0; ni < 3; ++ni) bk[ni] = *(const s16x8*)(bp + ni * 2048);
  }
#pragma unroll
  for (int mi = 0; mi < 4; ++mi) af[mi] = *(const s16x8*)(aP + mi * 1024);
  stage();
  if (VM == 2) asm volatile("s_waitcnt vmcnt(2)");
  if (VM == 0) asm volatile("s_waitcnt vmcnt(0)");
  __builtin_amdgcn_s_barrier();
  asm volatile("s_waitcnt lgkmcnt(0)");
  __builtin_amdgcn_s_setprio(1);
#pragma unroll
  for (int mi = 0; mi < 4; ++mi)
#pragma unroll
    for (int ni = 0; ni < 3; ++ni)
      acc[MH * 4 + mi][ni] =
          __builtin_amdgcn_mfma_f32_16x16x32_bf16(af[mi], bk[ni], acc[MH * 4 + mi][ni], 0, 0, 0);
  __builtin_amdgcn_s_setprio(0);
  __builtin_amdgcn_s_barrier();
}

template <int EPI, int TPB>
__device__ __forceinline__ void gemm192_body(
    const unsigned short* __restrict__ A, const unsigned short* __restrict__ Bt,
    void* __restrict__ outp, const float* __restrict__ bias,
    const void* __restrict__ resid, int M, int N, int K, int ntn) {
  __shared__ char ldsc[114688];  // 112 KiB
  int tid = threadIdx.x;
  int lane = tid & 63, w = tid >> 6;
  int wm = w >> 2, wn = w & 3;
  int fr = lane & 15, q = lane >> 4;

  int nwg = gridDim.x, orig = blockIdx.x;
  int qd = nwg >> 3, r8 = nwg & 7, xcd = orig & 7, loc = orig >> 3;
  int bid = (xcd < r8 ? xcd * (qd + 1) : r8 * (qd + 1) + (xcd - r8) * qd) + loc;

  // per-lane constant LDS addressing (hoisted across tiles)
  int rdoffA = (q * 16) ^ (((fr >> 1) & 3) << 4);
  const char* aB0 = ldsc + (wm * 128 + fr) * 64 + rdoffA;
  int brow0 = wn * 48 + fr;
  int bsw = brow0 & 7;
  const char* bBase = ldsc + 65536 + brow0 * 128 + (q ^ (bsw & 3)) * 16;
  const char* bKH0 = bBase + ((0 ^ (bsw >> 2)) * 64);
  const char* bKH1 = bBase + ((1 ^ (bsw >> 2)) * 64);

  int srow = tid >> 2;
  int seoffA = (((tid & 3) ^ ((srow >> 1) & 3))) << 3;
  size_t rstep = (size_t)K * 256;
  int NT = K / 64;

#pragma unroll 1
  for (int tl = 0; tl < TPB; ++tl) {
    int tile = bid * TPB + tl;
    int m0 = (tile / ntn) * 256, n0 = (tile % ntn) * 192;

    const char* Ab = (const char*)A + ((size_t)(m0 + srow) * K + seoffA) * 2;
    const char* Bb2 = (const char*)Bt +
        ((size_t)(n0 + (tid >> 3)) * K + (((tid & 7) ^ ((tid >> 3) & 7)) * 8)) * 2;

    auto stgA = [&](int kh, int buf, int t) {
      const char* gp = Ab + t * 128 + kh * 64;
      unsigned short* lp = (unsigned short*)(ldsc + buf * 32768 + kh * 16384 + w * 1024);
      gload16((const unsigned short*)gp, lp);
      gload16((const unsigned short*)(gp + rstep), (unsigned short*)((char*)lp + 8192));
    };
    auto stgB = [&](int j, int buf, int t) {
      gload16((const unsigned short*)(Bb2 + (size_t)j * 128 * K + t * 128),
              (unsigned short*)(ldsc + 65536 + buf * 24576 + j * 8192 + w * 1024));
    };
    auto nop = [&] {};

    f32x4 acc[8][3] = {};
    s16x8 bk[3];

    // prologue (stores from previous tile's C-write were issued BEFORE these
    // loads -> in-order vmcnt retirement drains them ahead of the loads;
    // counted waits below therefore track only the tracked loads)
    stgA(0, 0, 0);
    stgA(1, 0, 0);
    stgB(0, 0, 0);
    stgB(1, 0, 0);
    stgB(2, 0, 0);
    stgA(0, 1, 1);
    asm volatile("s_waitcnt vmcnt(2)");
    __builtin_amdgcn_s_barrier();

    for (int t = 0; t + 3 < NT; t += 2) {
      gph192<0, 0, 0, -1>(aB0, bKH0, bKH1, bk, acc,
                          [&] { stgA(1, 1, t + 1); stgB(0, 1, t + 1); stgB(1, 1, t + 1); });
      gph192<0, 1, 0, -1>(aB0, bKH0, bKH1, bk, acc, [&] { stgB(2, 1, t + 1); });
      gph192<0, 0, 1, -1>(aB0, bKH0, bKH1, bk, acc, [&] { stgA(0, 0, t + 2); });
      gph192<0, 1, 1, 2>(aB0, bKH0, bKH1, bk, acc, nop);
      gph192<1, 0, 0, -1>(aB0, bKH0, bKH1, bk, acc,
                          [&] { stgA(1, 0, t + 2); stgB(0, 0, t + 2); stgB(1, 0, t + 2); });
      gph192<1, 1, 0, -1>(aB0, bKH0, bKH1, bk, acc, [&] { stgB(2, 0, t + 2); });
      gph192<1, 0, 1, -1>(aB0, bKH0, bKH1, bk, acc, [&] { stgA(0, 1, t + 3); });
      gph192<1, 1, 1, 2>(aB0, bKH0, bKH1, bk, acc, nop);
    }
    gph192<0, 0, 0, -1>(aB0, bKH0, bKH1, bk, acc,
                        [&] { stgA(1, 1, NT - 1); stgB(0, 1, NT - 1); stgB(1, 1, NT - 1); });
    gph192<0, 1, 0, -1>(aB0, bKH0, bKH1, bk, acc, [&] { stgB(2, 1, NT - 1); });
    gph192<0, 0, 1, -1>(aB0, bKH0, bKH1, bk, acc, nop);
    gph192<0, 1, 1, 0>(aB0, bKH0, bKH1, bk, acc, nop);
    gph192<1, 0, 0, -1>(aB0, bKH0, bKH1, bk, acc, nop);
    gph192<1, 1, 0, -1>(aB0, bKH0, bKH1, bk, acc, nop);
    gph192<1, 0, 1, -1>(aB0, bKH0, bKH1, bk, acc, nop);
    gph192<1, 1, 1, -1>(aB0, bKH0, bKH1, bk, acc, nop);

    // C-write (after final phase's closing barrier, all LDS reads complete ->
    // next tile's prologue may overwrite LDS safely)
#pragma unroll
    for (int am = 0; am < 8; ++am)
#pragma unroll
      for (int ni = 0; ni < 3; ++ni)
#pragma unroll
        for (int rr = 0; rr < 4; ++rr) {
          int row = m0 + wm * 128 + am * 16 + q * 4 + rr;
          int col = n0 + wn * 48 + ni * 16 + fr;
          size_t idx = (size_t)row * N + col;
          epi_store(EPI, outp, idx, epi_apply(EPI, acc[am][ni][rr], col, idx, bias, resid));
        }
  }
}

// named wrappers for rocprof attribution
__global__ __launch_bounds__(512, 2) void gemm_qkv(const unsigned short* A,
                                                   const unsigned short* Bt, void* o,
                                                   const float* b, const void* r, int M,
                                                   int N, int K, int ntn) {
  gemm192_body<0, 3>(A, Bt, o, b, r, M, N, K, ntn);
}
__global__ __launch_bounds__(512, 2) void gemm_mlp1(const unsigned short* A,
                                                    const unsigned short* Bt, void* o,
                                                    const float* b, const void* r, int M,
                                                    int N, int K, int ntn) {
  gemm192_body<2, 4>(A, Bt, o, b, r, M, N, K, ntn);
}
__global__ __launch_bounds__(512, 2) void gemm_proj(const unsigned short* A,
                                                    const unsigned short* Bt, void* o,
                                                    const float* b, const void* r, int M,
                                                    int N, int K, int ntn) {
  gemm192_body<3, 1>(A, Bt, o, b, r, M, N, K, ntn);
}
__global__ __launch_bounds__(512, 2) void gemm_mlp2(const unsigned short* A,
                                                    const unsigned short* Bt, void* o,
                                                    const float* b, const void* r, int M,
                                                    int N, int K, int ntn) {
  gemm192_body<4, 1>(A, Bt, o, b, r, M, N, K, ntn);
}

// ---------------- MFMA attention: one wave per (batch, head) ----------------
__global__ __launch_bounds__(256) void attn_mfma_kernel(const unsigned short* __restrict__ qkv,
                                                        const float* __restrict__ scale,
                                                        unsigned short* __restrict__ ao) {
  __shared__ unsigned short Vt[4][64][40];
  __shared__ unsigned short Pl[4][32][32];
  int wid = threadIdx.x >> 6, lane = threadIdx.x & 63;
  int pair = blockIdx.x * 4 + wid;
  int b = pair / HEADS, h = pair % HEADS;
  const unsigned short* base = qkv + (size_t)b * NTOK * QKVN + h * DHEAD;
  const unsigned short* Qp = base;
  const unsigned short* Kp = base + 768;
  const unsigned short* Vp = base + 1536;

  int c = lane & 15, q = lane >> 4;
  int oct = q * 8;

  unsigned short vcol[NTOK];
#pragma unroll
  for (int j = 0; j < NTOK; ++j) vcol[j] = Vp[(size_t)j * QKVN + lane];
#pragma unroll
  for (int j = 0; j < NTOK; ++j) Vt[wid][lane][j] = vcol[j];
  Vt[wid][lane][31] = 0;

  s16x8 kf[2][2] = {{{0}}}, qf[2][2] = {{{0}}};
#pragma unroll
  for (int t = 0; t < 2; ++t) {
    int row = t * 16 + c;
    if (row < NTOK) {
#pragma unroll
      for (int s = 0; s < 2; ++s) {
        kf[t][s] = *(const s16x8*)(Kp + (size_t)row * QKVN + s * 32 + oct);
        qf[t][s] = *(const s16x8*)(Qp + (size_t)row * QKVN + s * 32 + oct);
      }
    }
  }

  f32x4 st[2][2] = {};
#pragma unroll
  for (int jt = 0; jt < 2; ++jt)
#pragma unroll
    for (int it = 0; it < 2; ++it)
#pragma unroll
      for (int s = 0; s < 2; ++s)
        st[jt][it] =
            __builtin_amdgcn_mfma_f32_16x16x32_bf16(kf[jt][s], qf[it][s], st[jt][it], 0, 0, 0);

  float scl = scale[h];
  float p[2][2][4];
#pragma unroll
  for (int it = 0; it < 2; ++it)
#pragma unroll
    for (int jt = 0; jt < 2; ++jt)
#pragma unroll
      for (int r = 0; r < 4; ++r) {
        int j = jt * 16 + 4 * q + r;
        int i = it * 16 + c;
        float v = st[jt][it][r] * scl;
        if (j == 31 || j == i) v = MASK_VAL;
        p[it][jt][r] = v;
      }
#pragma unroll
  for (int it = 0; it < 2; ++it) {
    float m = p[it][0][0];
#pragma unroll
    for (int jt = 0; jt < 2; ++jt)
#pragma unroll
      for (int r = 0; r < 4; ++r) m = fmaxf(m, p[it][jt][r]);
    m = fmaxf(m, __shfl_xor(m, 16));
    m = fmaxf(m, __shfl_xor(m, 32));
    float s = 0.f;
#pragma unroll
    for (int jt = 0; jt < 2; ++jt)
#pragma unroll
      for (int r = 0; r < 4; ++r) {
        float e = __expf(p[it][jt][r] - m);
        p[it][jt][r] = e;
        s += e;
      }
    s += __shfl_xor(s, 16);
    s += __shfl_xor(s, 32);
    float inv = __builtin_amdgcn_rcpf(s);
#pragma unroll
    for (int jt = 0; jt < 2; ++jt)
#pragma unroll
      for (int r = 0; r < 4; ++r) p[it][jt][r] *= inv;
  }
#pragma unroll
  for (int it = 0; it < 2; ++it)
#pragma unroll
    for (int jt = 0; jt < 2; ++jt) {
      unsigned int w0 =
          (unsigned int)f2bs(p[it][jt][0]) | ((unsigned int)f2bs(p[it][jt][1]) << 16);
      unsigned int w1 =
          (unsigned int)f2bs(p[it][jt][2]) | ((unsigned int)f2bs(p[it][jt][3]) << 16);
      uint2 pk = {w0, w1};
      *(uint2*)&Pl[wid][it * 16 + c][jt * 16 + 4 * q] = pk;
    }

  s16x8 pa[2];
#pragma unroll
  for (int it = 0; it < 2; ++it) pa[it] = *(const s16x8*)&Pl[wid][it * 16 + c][oct];
  f32x4 o[2][4];
#pragma unroll
  for (int it = 0; it < 2; ++it)
#pragma unroll
    for (int dt = 0; dt < 4; ++dt) {
      s16x8 vb = *(const s16x8*)&Vt[wid][dt * 16 + c][oct];
      f32x4 z = {0.f, 0.f, 0.f, 0.f};
      o[it][dt] = __builtin_amdgcn_mfma_f32_16x16x32_bf16(pa[it], vb, z, 0, 0, 0);
    }
#pragma unroll
  for (int it = 0; it < 2; ++it)
#pragma unroll
    for (int r = 0; r < 4; ++r) {
      int i = it * 16 + 4 * q + r;
      if (i < NTOK) {
        size_t rowoff = ((size_t)b * NTOK + i) * DIM + h * DHEAD;
#pragma unroll
        for (int dt = 0; dt < 4; ++dt) ao[rowoff + dt * 16 + c] = f2bs(o[it][dt][r]);
      }
    }
}

// ---------------- launcher ----------------
extern "C" void kernel_launch(void* const* d_in, const int* in_sizes, int n_in,
                              void* d_out, int out_size, void* d_ws, size_t ws_size,
                              hipStream_t stream) {
  (void)in_sizes; (void)n_in; (void)out_size; (void)ws_size;
  const float* x = (const float*)d_in[0];
  const float* ln1_g = (const float*)d_in[1];
  const float* ln1_b = (const float*)d_in[2];
  const float* w_qkv = (const float*)d_in[3];
  const float* scale = (const float*)d_in[4];
  const float* w_o = (const float*)d_in[5];
  const float* b_o = (const float*)d_in[6];
  const float* ln2_g = (const float*)d_in[7];
  const float* ln2_b = (const float*)d_in[8];
  const float* w1 = (const float*)d_in[9];
  const float* b1 = (const float*)d_in[10];
  const float* w2 = (const float*)d_in[11];
  const float* b2 = (const float*)d_in[12];

  char* ws = (char*)d_ws;
  unsigned short* buf1 = (unsigned short*)(ws + 0);
  unsigned short* qkv_bf = (unsigned short*)(ws + 24379392);
  unsigned short* x2 = (unsigned short*)(ws + 24379392);  // aliases qkv (qkv dead)
  unsigned short* g_bf = (unsigned short*)(ws + 97517568);
  unsigned short* wqkvT = (unsigned short*)(ws + 195035136);  // flat [2304][768]
  unsigned short* woT = (unsigned short*)(ws + 198574080);    // flat [768][768]
  unsigned short* w1T = (unsigned short*)(ws + 199753728);    // flat [3072][768]
  unsigned short* w2T = (unsigned short*)(ws + 204472320);    // flat [768][3072]

  transpose_all_kernel<<<1728, 256, 0, stream>>>(w_qkv, w_o, w1, w2, wqkvT, woT, w1T, w2T);

  ln_kernel<<<MTOK / 4, 256, 0, stream>>>(x, ln1_g, ln1_b, buf1);
  // qkv GEMM   [256x192, 744 tiles, TPB=3 -> grid 248]
  gemm_qkv<<<248, 512, 0, stream>>>(
      buf1, wqkvT, qkv_bf, nullptr, nullptr, MTOK, QKVN, DIM, QKVN / 192);
  attn_mfma_kernel<<<(BATCH * HEADS) / 4, 256, 0, stream>>>(qkv_bf, scale, buf1);
  // proj + residual(x, f32) -> x2 (bf16)   [248 tiles, TPB=1]
  gemm_proj<<<248, 512, 0, stream>>>(
      buf1, woT, x2, b_o, x, MTOK, DIM, DIM, DIM / 192);
  ln_bf16_kernel<<<MTOK / 4, 256, 0, stream>>>(x2, ln2_g, ln2_b, buf1);
  // mlp1 + tanh-GELU   [992 tiles, TPB=4 -> grid 248]
  gemm_mlp1<<<248, 512, 0, stream>>>(
      buf1, w1T, g_bf, b1, nullptr, MTOK, HIDDEN, DIM, HIDDEN / 192);
  // mlp2 + residual(x2, bf16) -> out (f32)   [248 tiles, TPB=1]
  gemm_mlp2<<<248, 512, 0, stream>>>(
      g_bf, w2T, (float*)d_out, b2, x2, MTOK, DIM, HIDDEN, DIM / 192);
}

// Round 15
// 310.351 us; speedup vs baseline: 1.0430x; 1.0092x over previous
//
#include <hip/hip_runtime.h>
#include <math.h>

#define DIM 768
#define HEADS 12
#define DHEAD 64
#define NTOK 31
#define BATCH 512
#define MTOK (BATCH * NTOK)   /* 15872 */
#define HIDDEN 3072
#define QKVN 2304
#define MASK_VAL -987654321.0f

typedef short s16x8 __attribute__((ext_vector_type(8)));
typedef float f32x4 __attribute__((ext_vector_type(4)));

static __device__ __forceinline__ float bs2f(unsigned short u) {
  unsigned int x = ((unsigned int)u) << 16;
  return __builtin_bit_cast(float, x);
}
static __device__ __forceinline__ unsigned short f2bs(float f) {
  unsigned int x = __builtin_bit_cast(unsigned int, f);
  x += 0x7fffu + ((x >> 16) & 1u);
  return (unsigned short)(x >> 16);
}

// async global->LDS, 16B per lane, wave-uniform LDS base + lane*16
static __device__ __forceinline__ void gload16(const unsigned short* g, unsigned short* l) {
  __builtin_amdgcn_global_load_lds(
      (const __attribute__((address_space(1))) unsigned int*)g,
      (__attribute__((address_space(3))) unsigned int*)l, 16, 0, 0);
}

static __device__ __forceinline__ float epi_apply(int EPI, float v, int col, size_t idx,
                                                  const float* bias, const void* resid) {
  if (EPI == 0) return v;
  if (EPI == 2) {
    float t = v + bias[col];
    float arg = 1.5957691216f * t * (1.f + 0.044715f * t * t);
    return t * __builtin_amdgcn_rcpf(1.f + __expf(-arg));
  }
  if (EPI == 3) return v + bias[col] + ((const float*)resid)[idx];
  return v + bias[col] + bs2f(((const unsigned short*)resid)[idx]);  // EPI==4
}

static __device__ __forceinline__ void epi_store(int EPI, void* outp, size_t idx, float t) {
  if (EPI == 4) ((float*)outp)[idx] = t;
  else ((unsigned short*)outp)[idx] = f2bs(t);
}

// ---------------- batched weight transposes: all flat [N][K] bf16 ----------------
__global__ __launch_bounds__(256) void transpose_all_kernel(
    const float* __restrict__ w_qkv, const float* __restrict__ w_o,
    const float* __restrict__ w1, const float* __restrict__ w2,
    unsigned short* __restrict__ wqkvT, unsigned short* __restrict__ woT,
    unsigned short* __restrict__ w1T, unsigned short* __restrict__ w2T) {
  int t = blockIdx.x;
  const float* w;
  unsigned short* wt;
  int K, N, tx;
  if (t < 432) { w = w_qkv; wt = wqkvT; K = DIM; N = QKVN; tx = QKVN / 64; }
  else if (t < 576) { t -= 432; w = w_o; wt = woT; K = DIM; N = DIM; tx = DIM / 64; }
  else if (t < 1152) { t -= 576; w = w1; wt = w1T; K = DIM; N = HIDDEN; tx = HIDDEN / 64; }
  else { t -= 1152; w = w2; wt = w2T; K = HIDDEN; N = DIM; tx = DIM / 64; }
  int n0 = (t % tx) * 64, k0 = (t / tx) * 64;

  __shared__ float tl[64][65];
  int tid = threadIdx.x;
  int r = tid >> 4, c4 = (tid & 15) * 4;
#pragma unroll
  for (int i = 0; i < 4; ++i) {
    float4 v = *(const float4*)(w + (size_t)(k0 + r + i * 16) * N + n0 + c4);
    tl[r + i * 16][c4] = v.x;
    tl[r + i * 16][c4 + 1] = v.y;
    tl[r + i * 16][c4 + 2] = v.z;
    tl[r + i * 16][c4 + 3] = v.w;
  }
  __syncthreads();
#pragma unroll
  for (int i = 0; i < 4; ++i) {
    int n = r + i * 16;
    ushort4 o;
    o.x = f2bs(tl[c4 + 0][n]);
    o.y = f2bs(tl[c4 + 1][n]);
    o.z = f2bs(tl[c4 + 2][n]);
    o.w = f2bs(tl[c4 + 3][n]);
    *(ushort4*)(wt + (size_t)(n0 + n) * K + k0 + c4) = o;
  }
}

// ---------------- LayerNorm (f32 in) ----------------
__global__ __launch_bounds__(256) void ln_kernel(const float* __restrict__ x,
                                                 const float* __restrict__ g,
                                                 const float* __restrict__ bta,
                                                 unsigned short* __restrict__ out) {
  int wid = threadIdx.x >> 6, lane = threadIdx.x & 63;
  size_t row = (size_t)blockIdx.x * 4 + wid;
  const float4* xr = (const float4*)(x + row * DIM);
  float4 v[3];
  v[0] = xr[lane];
  v[1] = xr[lane + 64];
  v[2] = xr[lane + 128];
  float s = 0.f, sq = 0.f;
#pragma unroll
  for (int i = 0; i < 3; ++i) {
    s += v[i].x + v[i].y + v[i].z + v[i].w;
    sq += v[i].x * v[i].x + v[i].y * v[i].y + v[i].z * v[i].z + v[i].w * v[i].w;
  }
#pragma unroll
  for (int off = 32; off; off >>= 1) {
    s += __shfl_xor(s, off);
    sq += __shfl_xor(sq, off);
  }
  float mu = s * (1.f / DIM);
  float var = sq * (1.f / DIM) - mu * mu;
  float rs = rsqrtf(var + 1e-5f);
#pragma unroll
  for (int i = 0; i < 3; ++i) {
    int col = i * 256 + lane * 4;
    float4 gg = *(const float4*)(g + col);
    float4 bb = *(const float4*)(bta + col);
    ushort4 o;
    o.x = f2bs((v[i].x - mu) * rs * gg.x + bb.x);
    o.y = f2bs((v[i].y - mu) * rs * gg.y + bb.y);
    o.z = f2bs((v[i].z - mu) * rs * gg.z + bb.z);
    o.w = f2bs((v[i].w - mu) * rs * gg.w + bb.w);
    *(ushort4*)(out + row * DIM + col) = o;
  }
}

// ---------------- LayerNorm (bf16 in) ----------------
__global__ __launch_bounds__(256) void ln_bf16_kernel(const unsigned short* __restrict__ x,
                                                      const float* __restrict__ g,
                                                      const float* __restrict__ bta,
                                                      unsigned short* __restrict__ out) {
  int wid = threadIdx.x >> 6, lane = threadIdx.x & 63;
  size_t row = (size_t)blockIdx.x * 4 + wid;
  const unsigned short* xr = x + row * DIM;
  float v[12];
#pragma unroll
  for (int i = 0; i < 3; ++i) {
    ushort4 u = *(const ushort4*)(xr + i * 256 + lane * 4);
    v[i * 4 + 0] = bs2f(u.x);
    v[i * 4 + 1] = bs2f(u.y);
    v[i * 4 + 2] = bs2f(u.z);
    v[i * 4 + 3] = bs2f(u.w);
  }
  float s = 0.f, sq = 0.f;
#pragma unroll
  for (int i = 0; i < 12; ++i) {
    s += v[i];
    sq += v[i] * v[i];
  }
#pragma unroll
  for (int off = 32; off; off >>= 1) {
    s += __shfl_xor(s, off);
    sq += __shfl_xor(sq, off);
  }
  float mu = s * (1.f / DIM);
  float var = sq * (1.f / DIM) - mu * mu;
  float rs = rsqrtf(var + 1e-5f);
#pragma unroll
  for (int i = 0; i < 3; ++i) {
    int col = i * 256 + lane * 4;
    float4 gg = *(const float4*)(g + col);
    float4 bb = *(const float4*)(bta + col);
    ushort4 o;
    o.x = f2bs((v[i * 4 + 0] - mu) * rs * gg.x + bb.x);
    o.y = f2bs((v[i * 4 + 1] - mu) * rs * gg.y + bb.y);
    o.z = f2bs((v[i * 4 + 2] - mu) * rs * gg.z + bb.z);
    o.w = f2bs((v[i * 4 + 3] - mu) * rs * gg.w + bb.w);
    *(ushort4*)(out + row * DIM + col) = o;
  }
}

// ============ pipelined persistent 8-phase 256x192 GEMM (all four GEMMs) ============
// Frag regs double-buffered: phase p's MFMA uses regs read in phase p-1; the
// ds_reads for p+1 issue right after barrier1(p) and drain UNDER p's MFMA.
// No explicit lgkmcnt: compiler emits per-operand waits (old regset = complete).
// Stage/vmcnt/barrier placement identical to the proven R14 ledger; reads moved
// from top-of-phase-q to post-B1-of-(q-1) -- every confirm (pre-B1) still
// precedes its reads.
// CMH: acc row base; CS: af set used; CB: bk set used; R*: next phase's source
// (RB = bk set to fill when RMH==0); VM: vmcnt; NORD: skip read-ahead.
template <int CMH, int CS, int CB, int RBUF, int RMH, int RKH, int RB, int VM, int NORD,
          typename STF>
__device__ __forceinline__ void gphP(const char* aB0, const char* bKH0, const char* bKH1,
                                     s16x8 (&af2)[2][4], s16x8 (&bk2)[2][3],
                                     f32x4 (&acc)[8][3], STF&& stage) {
  stage();
  if (VM == 2) asm volatile("s_waitcnt vmcnt(2)");
  if (VM == 0) asm volatile("s_waitcnt vmcnt(0)");
  __builtin_amdgcn_s_barrier();
  if (!NORD) {
    const char* aP = aB0 + RBUF * 32768 + RKH * 16384 + RMH * 4096;
#pragma unroll
    for (int mi = 0; mi < 4; ++mi) af2[CS ^ 1][mi] = *(const s16x8*)(aP + mi * 1024);
    if (RMH == 0) {
      const char* bp = (RKH ? bKH1 : bKH0) + RBUF * 24576;
#pragma unroll
      for (int ni = 0; ni < 3; ++ni) bk2[RB][ni] = *(const s16x8*)(bp + ni * 2048);
    }
  }
  __builtin_amdgcn_s_setprio(1);
#pragma unroll
  for (int mi = 0; mi < 4; ++mi)
#pragma unroll
    for (int ni = 0; ni < 3; ++ni)
      acc[CMH * 4 + mi][ni] = __builtin_amdgcn_mfma_f32_16x16x32_bf16(
          af2[CS][mi], bk2[CB][ni], acc[CMH * 4 + mi][ni], 0, 0, 0);
  __builtin_amdgcn_s_setprio(0);
  __builtin_amdgcn_s_barrier();
}

template <int EPI, int TPB>
__device__ __forceinline__ void gemm192_body(
    const unsigned short* __restrict__ A, const unsigned short* __restrict__ Bt,
    void* __restrict__ outp, const float* __restrict__ bias,
    const void* __restrict__ resid, int M, int N, int K, int ntn) {
  __shared__ char ldsc[114688];  // 112 KiB
  int tid = threadIdx.x;
  int lane = tid & 63, w = tid >> 6;
  int wm = w >> 2, wn = w & 3;
  int fr = lane & 15, q = lane >> 4;

  int nwg = gridDim.x, orig = blockIdx.x;
  int qd = nwg >> 3, r8 = nwg & 7, xcd = orig & 7, loc = orig >> 3;
  int bid = (xcd < r8 ? xcd * (qd + 1) : r8 * (qd + 1) + (xcd - r8) * qd) + loc;

  int rdoffA = (q * 16) ^ (((fr >> 1) & 3) << 4);
  const char* aB0 = ldsc + (wm * 128 + fr) * 64 + rdoffA;
  int brow0 = wn * 48 + fr;
  int bsw = brow0 & 7;
  const char* bBase = ldsc + 65536 + brow0 * 128 + (q ^ (bsw & 3)) * 16;
  const char* bKH0 = bBase + ((0 ^ (bsw >> 2)) * 64);
  const char* bKH1 = bBase + ((1 ^ (bsw >> 2)) * 64);

  int srow = tid >> 2;
  int seoffA = (((tid & 3) ^ ((srow >> 1) & 3))) << 3;
  size_t rstep = (size_t)K * 256;
  int NT = K / 64;

#pragma unroll 1
  for (int tl = 0; tl < TPB; ++tl) {
    int tile = bid * TPB + tl;
    int m0 = (tile / ntn) * 256, n0 = (tile % ntn) * 192;

    const char* Ab = (const char*)A + ((size_t)(m0 + srow) * K + seoffA) * 2;
    const char* Bb2 = (const char*)Bt +
        ((size_t)(n0 + (tid >> 3)) * K + (((tid & 7) ^ ((tid >> 3) & 7)) * 8)) * 2;

    auto stgA = [&](int kh, int buf, int t) {
      const char* gp = Ab + t * 128 + kh * 64;
      unsigned short* lp = (unsigned short*)(ldsc + buf * 32768 + kh * 16384 + w * 1024);
      gload16((const unsigned short*)gp, lp);
      gload16((const unsigned short*)(gp + rstep), (unsigned short*)((char*)lp + 8192));
    };
    auto stgB = [&](int j, int buf, int t) {
      gload16((const unsigned short*)(Bb2 + (size_t)j * 128 * K + t * 128),
              (unsigned short*)(ldsc + 65536 + buf * 24576 + j * 8192 + w * 1024));
    };
    auto nop = [&] {};

    f32x4 acc[8][3] = {};
    s16x8 af2[2][4], bk2[2][3];

    // prologue: stage tile0 fully + tile1 A-kh0; confirm buf0; preload frags(ph0)
    stgA(0, 0, 0);
    stgA(1, 0, 0);
    stgB(0, 0, 0);
    stgB(1, 0, 0);
    stgB(2, 0, 0);
    stgA(0, 1, 1);
    asm volatile("s_waitcnt vmcnt(2)");
    __builtin_amdgcn_s_barrier();
    {
#pragma unroll
      for (int mi = 0; mi < 4; ++mi) af2[0][mi] = *(const s16x8*)(aB0 + mi * 1024);
#pragma unroll
      for (int ni = 0; ni < 3; ++ni) bk2[0][ni] = *(const s16x8*)(bKH0 + ni * 2048);
    }

    for (int t = 0; t + 3 < NT; t += 2) {
      gphP<0, 0, 0, 0, 1, 0, 0, -1, 0>(aB0, bKH0, bKH1, af2, bk2, acc,
          [&] { stgA(1, 1, t + 1); stgB(0, 1, t + 1); stgB(1, 1, t + 1); });
      gphP<1, 1, 0, 0, 0, 1, 1, -1, 0>(aB0, bKH0, bKH1, af2, bk2, acc,
          [&] { stgB(2, 1, t + 1); });
      gphP<0, 0, 1, 0, 1, 1, 0, -1, 0>(aB0, bKH0, bKH1, af2, bk2, acc,
          [&] { stgA(0, 0, t + 2); });
      gphP<1, 1, 1, 1, 0, 0, 0, 2, 0>(aB0, bKH0, bKH1, af2, bk2, acc, nop);
      gphP<0, 0, 0, 1, 1, 0, 0, -1, 0>(aB0, bKH0, bKH1, af2, bk2, acc,
          [&] { stgA(1, 0, t + 2); stgB(0, 0, t + 2); stgB(1, 0, t + 2); });
      gphP<1, 1, 0, 1, 0, 1, 1, -1, 0>(aB0, bKH0, bKH1, af2, bk2, acc,
          [&] { stgB(2, 0, t + 2); });
      gphP<0, 0, 1, 1, 1, 1, 0, -1, 0>(aB0, bKH0, bKH1, af2, bk2, acc,
          [&] { stgA(0, 1, t + 3); });
      gphP<1, 1, 1, 0, 0, 0, 0, 2, 0>(aB0, bKH0, bKH1, af2, bk2, acc, nop);
    }
    // epilogue: tiles NT-2, NT-1
    gphP<0, 0, 0, 0, 1, 0, 0, -1, 0>(aB0, bKH0, bKH1, af2, bk2, acc,
        [&] { stgA(1, 1, NT - 1); stgB(0, 1, NT - 1); stgB(1, 1, NT - 1); });
    gphP<1, 1, 0, 0, 0, 1, 1, -1, 0>(aB0, bKH0, bKH1, af2, bk2, acc,
        [&] { stgB(2, 1, NT - 1); });
    gphP<0, 0, 1, 0, 1, 1, 0, -1, 0>(aB0, bKH0, bKH1, af2, bk2, acc, nop);
    gphP<1, 1, 1, 1, 0, 0, 0, 0, 0>(aB0, bKH0, bKH1, af2, bk2, acc, nop);
    gphP<0, 0, 0, 1, 1, 0, 0, -1, 0>(aB0, bKH0, bKH1, af2, bk2, acc, nop);
    gphP<1, 1, 0, 1, 0, 1, 1, -1, 0>(aB0, bKH0, bKH1, af2, bk2, acc, nop);
    gphP<0, 0, 1, 1, 1, 1, 0, -1, 0>(aB0, bKH0, bKH1, af2, bk2, acc, nop);
    gphP<1, 1, 1, 0, 0, 0, 0, -1, 1>(aB0, bKH0, bKH1, af2, bk2, acc, nop);

    // C-write
#pragma unroll
    for (int am = 0; am < 8; ++am)
#pragma unroll
      for (int ni = 0; ni < 3; ++ni)
#pragma unroll
        for (int rr = 0; rr < 4; ++rr) {
          int row = m0 + wm * 128 + am * 16 + q * 4 + rr;
          int col = n0 + wn * 48 + ni * 16 + fr;
          size_t idx = (size_t)row * N + col;
          epi_store(EPI, outp, idx, epi_apply(EPI, acc[am][ni][rr], col, idx, bias, resid));
        }
  }
}

// named wrappers for rocprof attribution
__global__ __launch_bounds__(512, 2) void gemm_qkv(const unsigned short* A,
                                                   const unsigned short* Bt, void* o,
                                                   const float* b, const void* r, int M,
                                                   int N, int K, int ntn) {
  gemm192_body<0, 3>(A, Bt, o, b, r, M, N, K, ntn);
}
__global__ __launch_bounds__(512, 2) void gemm_mlp1(const unsigned short* A,
                                                    const unsigned short* Bt, void* o,
                                                    const float* b, const void* r, int M,
                                                    int N, int K, int ntn) {
  gemm192_body<2, 4>(A, Bt, o, b, r, M, N, K, ntn);
}
__global__ __launch_bounds__(512, 2) void gemm_proj(const unsigned short* A,
                                                    const unsigned short* Bt, void* o,
                                                    const float* b, const void* r, int M,
                                                    int N, int K, int ntn) {
  gemm192_body<3, 1>(A, Bt, o, b, r, M, N, K, ntn);
}
__global__ __launch_bounds__(512, 2) void gemm_mlp2(const unsigned short* A,
                                                    const unsigned short* Bt, void* o,
                                                    const float* b, const void* r, int M,
                                                    int N, int K, int ntn) {
  gemm192_body<4, 1>(A, Bt, o, b, r, M, N, K, ntn);
}

// ---------------- MFMA attention: one wave per (batch, head) ----------------
__global__ __launch_bounds__(256) void attn_mfma_kernel(const unsigned short* __restrict__ qkv,
                                                        const float* __restrict__ scale,
                                                        unsigned short* __restrict__ ao) {
  __shared__ unsigned short Vt[4][64][40];
  __shared__ unsigned short Pl[4][32][32];
  int wid = threadIdx.x >> 6, lane = threadIdx.x & 63;
  int pair = blockIdx.x * 4 + wid;
  int b = pair / HEADS, h = pair % HEADS;
  const unsigned short* base = qkv + (size_t)b * NTOK * QKVN + h * DHEAD;
  const unsigned short* Qp = base;
  const unsigned short* Kp = base + 768;
  const unsigned short* Vp = base + 1536;

  int c = lane & 15, q = lane >> 4;
  int oct = q * 8;

  unsigned short vcol[NTOK];
#pragma unroll
  for (int j = 0; j < NTOK; ++j) vcol[j] = Vp[(size_t)j * QKVN + lane];
#pragma unroll
  for (int j = 0; j < NTOK; ++j) Vt[wid][lane][j] = vcol[j];
  Vt[wid][lane][31] = 0;

  s16x8 kf[2][2] = {{{0}}}, qf[2][2] = {{{0}}};
#pragma unroll
  for (int t = 0; t < 2; ++t) {
    int row = t * 16 + c;
    if (row < NTOK) {
#pragma unroll
      for (int s = 0; s < 2; ++s) {
        kf[t][s] = *(const s16x8*)(Kp + (size_t)row * QKVN + s * 32 + oct);
        qf[t][s] = *(const s16x8*)(Qp + (size_t)row * QKVN + s * 32 + oct);
      }
    }
  }

  f32x4 st[2][2] = {};
#pragma unroll
  for (int jt = 0; jt < 2; ++jt)
#pragma unroll
    for (int it = 0; it < 2; ++it)
#pragma unroll
      for (int s = 0; s < 2; ++s)
        st[jt][it] =
            __builtin_amdgcn_mfma_f32_16x16x32_bf16(kf[jt][s], qf[it][s], st[jt][it], 0, 0, 0);

  float scl = scale[h];
  float p[2][2][4];
#pragma unroll
  for (int it = 0; it < 2; ++it)
#pragma unroll
    for (int jt = 0; jt < 2; ++jt)
#pragma unroll
      for (int r = 0; r < 4; ++r) {
        int j = jt * 16 + 4 * q + r;
        int i = it * 16 + c;
        float v = st[jt][it][r] * scl;
        if (j == 31 || j == i) v = MASK_VAL;
        p[it][jt][r] = v;
      }
#pragma unroll
  for (int it = 0; it < 2; ++it) {
    float m = p[it][0][0];
#pragma unroll
    for (int jt = 0; jt < 2; ++jt)
#pragma unroll
      for (int r = 0; r < 4; ++r) m = fmaxf(m, p[it][jt][r]);
    m = fmaxf(m, __shfl_xor(m, 16));
    m = fmaxf(m, __shfl_xor(m, 32));
    float s = 0.f;
#pragma unroll
    for (int jt = 0; jt < 2; ++jt)
#pragma unroll
      for (int r = 0; r < 4; ++r) {
        float e = __expf(p[it][jt][r] - m);
        p[it][jt][r] = e;
        s += e;
      }
    s += __shfl_xor(s, 16);
    s += __shfl_xor(s, 32);
    float inv = __builtin_amdgcn_rcpf(s);
#pragma unroll
    for (int jt = 0; jt < 2; ++jt)
#pragma unroll
      for (int r = 0; r < 4; ++r) p[it][jt][r] *= inv;
  }
#pragma unroll
  for (int it = 0; it < 2; ++it)
#pragma unroll
    for (int jt = 0; jt < 2; ++jt) {
      unsigned int w0 =
          (unsigned int)f2bs(p[it][jt][0]) | ((unsigned int)f2bs(p[it][jt][1]) << 16);
      unsigned int w1 =
          (unsigned int)f2bs(p[it][jt][2]) | ((unsigned int)f2bs(p[it][jt][3]) << 16);
      uint2 pk = {w0, w1};
      *(uint2*)&Pl[wid][it * 16 + c][jt * 16 + 4 * q] = pk;
    }

  s16x8 pa[2];
#pragma unroll
  for (int it = 0; it < 2; ++it) pa[it] = *(const s16x8*)&Pl[wid][it * 16 + c][oct];
  f32x4 o[2][4];
#pragma unroll
  for (int it = 0; it < 2; ++it)
#pragma unroll
    for (int dt = 0; dt < 4; ++dt) {
      s16x8 vb = *(const s16x8*)&Vt[wid][dt * 16 + c][oct];
      f32x4 z = {0.f, 0.f, 0.f, 0.f};
      o[it][dt] = __builtin_amdgcn_mfma_f32_16x16x32_bf16(pa[it], vb, z, 0, 0, 0);
    }
#pragma unroll
  for (int it = 0; it < 2; ++it)
#pragma unroll
    for (int r = 0; r < 4; ++r) {
      int i = it * 16 + 4 * q + r;
      if (i < NTOK) {
        size_t rowoff = ((size_t)b * NTOK + i) * DIM + h * DHEAD;
#pragma unroll
        for (int dt = 0; dt < 4; ++dt) ao[rowoff + dt * 16 + c] = f2bs(o[it][dt][r]);
      }
    }
}

// ---------------- launcher ----------------
extern "C" void kernel_launch(void* const* d_in, const int* in_sizes, int n_in,
                              void* d_out, int out_size, void* d_ws, size_t ws_size,
                              hipStream_t stream) {
  (void)in_sizes; (void)n_in; (void)out_size; (void)ws_size;
  const float* x = (const float*)d_in[0];
  const float* ln1_g = (const float*)d_in[1];
  const float* ln1_b = (const float*)d_in[2];
  const float* w_qkv = (const float*)d_in[3];
  const float* scale = (const float*)d_in[4];
  const float* w_o = (const float*)d_in[5];
  const float* b_o = (const float*)d_in[6];
  const float* ln2_g = (const float*)d_in[7];
  const float* ln2_b = (const float*)d_in[8];
  const float* w1 = (const float*)d_in[9];
  const float* b1 = (const float*)d_in[10];
  const float* w2 = (const float*)d_in[11];
  const float* b2 = (const float*)d_in[12];

  char* ws = (char*)d_ws;
  unsigned short* buf1 = (unsigned short*)(ws + 0);
  unsigned short* qkv_bf = (unsigned short*)(ws + 24379392);
  unsigned short* x2 = (unsigned short*)(ws + 24379392);  // aliases qkv (qkv dead)
  unsigned short* g_bf = (unsigned short*)(ws + 97517568);
  unsigned short* wqkvT = (unsigned short*)(ws + 195035136);  // flat [2304][768]
  unsigned short* woT = (unsigned short*)(ws + 198574080);    // flat [768][768]
  unsigned short* w1T = (unsigned short*)(ws + 199753728);    // flat [3072][768]
  unsigned short* w2T = (unsigned short*)(ws + 204472320);    // flat [768][3072]

  transpose_all_kernel<<<1728, 256, 0, stream>>>(w_qkv, w_o, w1, w2, wqkvT, woT, w1T, w2T);

  ln_kernel<<<MTOK / 4, 256, 0, stream>>>(x, ln1_g, ln1_b, buf1);
  // qkv GEMM   [256x192, 744 tiles, TPB=3 -> grid 248]
  gemm_qkv<<<248, 512, 0, stream>>>(
      buf1, wqkvT, qkv_bf, nullptr, nullptr, MTOK, QKVN, DIM, QKVN / 192);
  attn_mfma_kernel<<<(BATCH * HEADS) / 4, 256, 0, stream>>>(qkv_bf, scale, buf1);
  // proj + residual(x, f32) -> x2 (bf16)   [248 tiles, TPB=1]
  gemm_proj<<<248, 512, 0, stream>>>(
      buf1, woT, x2, b_o, x, MTOK, DIM, DIM, DIM / 192);
  ln_bf16_kernel<<<MTOK / 4, 256, 0, stream>>>(x2, ln2_g, ln2_b, buf1);
  // mlp1 + tanh-GELU   [992 tiles, TPB=4 -> grid 248]
  gemm_mlp1<<<248, 512, 0, stream>>>(
      buf1, w1T, g_bf, b1, nullptr, MTOK, HIDDEN, DIM, HIDDEN / 192);
  // mlp2 + residual(x2, bf16) -> out (f32)   [248 tiles, TPB=1]
  gemm_mlp2<<<248, 512, 0, stream>>>(
      g_bf, w2T, (float*)d_out, b2, x2, MTOK, DIM, HIDDEN, DIM / 192);
}

// Round 16
// 305.896 us; speedup vs baseline: 1.0582x; 1.0146x over previous
//
#include <hip/hip_runtime.h>
#include <math.h>

#define DIM 768
#define HEADS 12
#define DHEAD 64
#define NTOK 31
#define BATCH 512
#define MTOK (BATCH * NTOK)   /* 15872 */
#define HIDDEN 3072
#define QKVN 2304
#define MASK_VAL -987654321.0f

typedef short s16x8 __attribute__((ext_vector_type(8)));
typedef float f32x4 __attribute__((ext_vector_type(4)));

static __device__ __forceinline__ float bs2f(unsigned short u) {
  unsigned int x = ((unsigned int)u) << 16;
  return __builtin_bit_cast(float, x);
}
static __device__ __forceinline__ unsigned short f2bs(float f) {
  unsigned int x = __builtin_bit_cast(unsigned int, f);
  x += 0x7fffu + ((x >> 16) & 1u);
  return (unsigned short)(x >> 16);
}

// async global->LDS, 16B per lane, wave-uniform LDS base + lane*16
static __device__ __forceinline__ void gload16(const unsigned short* g, unsigned short* l) {
  __builtin_amdgcn_global_load_lds(
      (const __attribute__((address_space(1))) unsigned int*)g,
      (__attribute__((address_space(3))) unsigned int*)l, 16, 0, 0);
}

static __device__ __forceinline__ float epi_apply(int EPI, float v, int col, size_t idx,
                                                  const float* bias, const void* resid) {
  if (EPI == 0) return v;
  if (EPI == 2) {
    float t = v + bias[col];
    float arg = 1.5957691216f * t * (1.f + 0.044715f * t * t);
    return t * __builtin_amdgcn_rcpf(1.f + __expf(-arg));
  }
  if (EPI == 3) return v + bias[col] + ((const float*)resid)[idx];
  return v + bias[col] + bs2f(((const unsigned short*)resid)[idx]);  // EPI==4
}

static __device__ __forceinline__ void epi_store(int EPI, void* outp, size_t idx, float t) {
  if (EPI == 4) ((float*)outp)[idx] = t;
  else ((unsigned short*)outp)[idx] = f2bs(t);
}

// ---------------- batched weight transposes: all flat [N][K] bf16 ----------------
__global__ __launch_bounds__(256) void transpose_all_kernel(
    const float* __restrict__ w_qkv, const float* __restrict__ w_o,
    const float* __restrict__ w1, const float* __restrict__ w2,
    unsigned short* __restrict__ wqkvT, unsigned short* __restrict__ woT,
    unsigned short* __restrict__ w1T, unsigned short* __restrict__ w2T) {
  int t = blockIdx.x;
  const float* w;
  unsigned short* wt;
  int K, N, tx;
  if (t < 432) { w = w_qkv; wt = wqkvT; K = DIM; N = QKVN; tx = QKVN / 64; }
  else if (t < 576) { t -= 432; w = w_o; wt = woT; K = DIM; N = DIM; tx = DIM / 64; }
  else if (t < 1152) { t -= 576; w = w1; wt = w1T; K = DIM; N = HIDDEN; tx = HIDDEN / 64; }
  else { t -= 1152; w = w2; wt = w2T; K = HIDDEN; N = DIM; tx = DIM / 64; }
  int n0 = (t % tx) * 64, k0 = (t / tx) * 64;

  __shared__ float tl[64][65];
  int tid = threadIdx.x;
  int r = tid >> 4, c4 = (tid & 15) * 4;
#pragma unroll
  for (int i = 0; i < 4; ++i) {
    float4 v = *(const float4*)(w + (size_t)(k0 + r + i * 16) * N + n0 + c4);
    tl[r + i * 16][c4] = v.x;
    tl[r + i * 16][c4 + 1] = v.y;
    tl[r + i * 16][c4 + 2] = v.z;
    tl[r + i * 16][c4 + 3] = v.w;
  }
  __syncthreads();
#pragma unroll
  for (int i = 0; i < 4; ++i) {
    int n = r + i * 16;
    ushort4 o;
    o.x = f2bs(tl[c4 + 0][n]);
    o.y = f2bs(tl[c4 + 1][n]);
    o.z = f2bs(tl[c4 + 2][n]);
    o.w = f2bs(tl[c4 + 3][n]);
    *(ushort4*)(wt + (size_t)(n0 + n) * K + k0 + c4) = o;
  }
}

// ---------------- LayerNorm (f32 in) ----------------
__global__ __launch_bounds__(256) void ln_kernel(const float* __restrict__ x,
                                                 const float* __restrict__ g,
                                                 const float* __restrict__ bta,
                                                 unsigned short* __restrict__ out) {
  int wid = threadIdx.x >> 6, lane = threadIdx.x & 63;
  size_t row = (size_t)blockIdx.x * 4 + wid;
  const float4* xr = (const float4*)(x + row * DIM);
  float4 v[3];
  v[0] = xr[lane];
  v[1] = xr[lane + 64];
  v[2] = xr[lane + 128];
  float s = 0.f, sq = 0.f;
#pragma unroll
  for (int i = 0; i < 3; ++i) {
    s += v[i].x + v[i].y + v[i].z + v[i].w;
    sq += v[i].x * v[i].x + v[i].y * v[i].y + v[i].z * v[i].z + v[i].w * v[i].w;
  }
#pragma unroll
  for (int off = 32; off; off >>= 1) {
    s += __shfl_xor(s, off);
    sq += __shfl_xor(sq, off);
  }
  float mu = s * (1.f / DIM);
  float var = sq * (1.f / DIM) - mu * mu;
  float rs = rsqrtf(var + 1e-5f);
#pragma unroll
  for (int i = 0; i < 3; ++i) {
    int col = i * 256 + lane * 4;
    float4 gg = *(const float4*)(g + col);
    float4 bb = *(const float4*)(bta + col);
    ushort4 o;
    o.x = f2bs((v[i].x - mu) * rs * gg.x + bb.x);
    o.y = f2bs((v[i].y - mu) * rs * gg.y + bb.y);
    o.z = f2bs((v[i].z - mu) * rs * gg.z + bb.z);
    o.w = f2bs((v[i].w - mu) * rs * gg.w + bb.w);
    *(ushort4*)(out + row * DIM + col) = o;
  }
}

// ---------------- LayerNorm (bf16 in) ----------------
__global__ __launch_bounds__(256) void ln_bf16_kernel(const unsigned short* __restrict__ x,
                                                      const float* __restrict__ g,
                                                      const float* __restrict__ bta,
                                                      unsigned short* __restrict__ out) {
  int wid = threadIdx.x >> 6, lane = threadIdx.x & 63;
  size_t row = (size_t)blockIdx.x * 4 + wid;
  const unsigned short* xr = x + row * DIM;
  float v[12];
#pragma unroll
  for (int i = 0; i < 3; ++i) {
    ushort4 u = *(const ushort4*)(xr + i * 256 + lane * 4);
    v[i * 4 + 0] = bs2f(u.x);
    v[i * 4 + 1] = bs2f(u.y);
    v[i * 4 + 2] = bs2f(u.z);
    v[i * 4 + 3] = bs2f(u.w);
  }
  float s = 0.f, sq = 0.f;
#pragma unroll
  for (int i = 0; i < 12; ++i) {
    s += v[i];
    sq += v[i] * v[i];
  }
#pragma unroll
  for (int off = 32; off; off >>= 1) {
    s += __shfl_xor(s, off);
    sq += __shfl_xor(sq, off);
  }
  float mu = s * (1.f / DIM);
  float var = sq * (1.f / DIM) - mu * mu;
  float rs = rsqrtf(var + 1e-5f);
#pragma unroll
  for (int i = 0; i < 3; ++i) {
    int col = i * 256 + lane * 4;
    float4 gg = *(const float4*)(g + col);
    float4 bb = *(const float4*)(bta + col);
    ushort4 o;
    o.x = f2bs((v[i * 4 + 0] - mu) * rs * gg.x + bb.x);
    o.y = f2bs((v[i * 4 + 1] - mu) * rs * gg.y + bb.y);
    o.z = f2bs((v[i * 4 + 2] - mu) * rs * gg.z + bb.z);
    o.w = f2bs((v[i * 4 + 3] - mu) * rs * gg.w + bb.w);
    *(ushort4*)(out + row * DIM + col) = o;
  }
}

// ============ pipelined persistent 8-phase 256x192 GEMM (qkv, proj, mlp2) ============
template <int CMH, int CS, int CB, int RBUF, int RMH, int RKH, int RB, int VM, int NORD,
          typename STF>
__device__ __forceinline__ void gphP(const char* aB0, const char* bKH0, const char* bKH1,
                                     s16x8 (&af2)[2][4], s16x8 (&bk2)[2][3],
                                     f32x4 (&acc)[8][3], STF&& stage) {
  stage();
  if (VM == 2) asm volatile("s_waitcnt vmcnt(2)");
  if (VM == 0) asm volatile("s_waitcnt vmcnt(0)");
  __builtin_amdgcn_s_barrier();
  if (!NORD) {
    const char* aP = aB0 + RBUF * 32768 + RKH * 16384 + RMH * 4096;
#pragma unroll
    for (int mi = 0; mi < 4; ++mi) af2[CS ^ 1][mi] = *(const s16x8*)(aP + mi * 1024);
    if (RMH == 0) {
      const char* bp = (RKH ? bKH1 : bKH0) + RBUF * 24576;
#pragma unroll
      for (int ni = 0; ni < 3; ++ni) bk2[RB][ni] = *(const s16x8*)(bp + ni * 2048);
    }
  }
  __builtin_amdgcn_s_setprio(1);
#pragma unroll
  for (int mi = 0; mi < 4; ++mi)
#pragma unroll
    for (int ni = 0; ni < 3; ++ni)
      acc[CMH * 4 + mi][ni] = __builtin_amdgcn_mfma_f32_16x16x32_bf16(
          af2[CS][mi], bk2[CB][ni], acc[CMH * 4 + mi][ni], 0, 0, 0);
  __builtin_amdgcn_s_setprio(0);
  __builtin_amdgcn_s_barrier();
}

template <int EPI, int TPB>
__device__ __forceinline__ void gemm192_body(
    const unsigned short* __restrict__ A, const unsigned short* __restrict__ Bt,
    void* __restrict__ outp, const float* __restrict__ bias,
    const void* __restrict__ resid, int M, int N, int K, int ntn) {
  __shared__ char ldsc[114688];  // 112 KiB
  int tid = threadIdx.x;
  int lane = tid & 63, w = tid >> 6;
  int wm = w >> 2, wn = w & 3;
  int fr = lane & 15, q = lane >> 4;

  int nwg = gridDim.x, orig = blockIdx.x;
  int qd = nwg >> 3, r8 = nwg & 7, xcd = orig & 7, loc = orig >> 3;
  int bid = (xcd < r8 ? xcd * (qd + 1) : r8 * (qd + 1) + (xcd - r8) * qd) + loc;

  int rdoffA = (q * 16) ^ (((fr >> 1) & 3) << 4);
  const char* aB0 = ldsc + (wm * 128 + fr) * 64 + rdoffA;
  int brow0 = wn * 48 + fr;
  int bsw = brow0 & 7;
  const char* bBase = ldsc + 65536 + brow0 * 128 + (q ^ (bsw & 3)) * 16;
  const char* bKH0 = bBase + ((0 ^ (bsw >> 2)) * 64);
  const char* bKH1 = bBase + ((1 ^ (bsw >> 2)) * 64);

  int srow = tid >> 2;
  int seoffA = (((tid & 3) ^ ((srow >> 1) & 3))) << 3;
  size_t rstep = (size_t)K * 256;
  int NT = K / 64;

#pragma unroll 1
  for (int tl = 0; tl < TPB; ++tl) {
    int tile = bid * TPB + tl;
    int m0 = (tile / ntn) * 256, n0 = (tile % ntn) * 192;

    const char* Ab = (const char*)A + ((size_t)(m0 + srow) * K + seoffA) * 2;
    const char* Bb2 = (const char*)Bt +
        ((size_t)(n0 + (tid >> 3)) * K + (((tid & 7) ^ ((tid >> 3) & 7)) * 8)) * 2;

    auto stgA = [&](int kh, int buf, int t) {
      const char* gp = Ab + t * 128 + kh * 64;
      unsigned short* lp = (unsigned short*)(ldsc + buf * 32768 + kh * 16384 + w * 1024);
      gload16((const unsigned short*)gp, lp);
      gload16((const unsigned short*)(gp + rstep), (unsigned short*)((char*)lp + 8192));
    };
    auto stgB = [&](int j, int buf, int t) {
      gload16((const unsigned short*)(Bb2 + (size_t)j * 128 * K + t * 128),
              (unsigned short*)(ldsc + 65536 + buf * 24576 + j * 8192 + w * 1024));
    };
    auto nop = [&] {};

    f32x4 acc[8][3] = {};
    s16x8 af2[2][4], bk2[2][3];

    stgA(0, 0, 0);
    stgA(1, 0, 0);
    stgB(0, 0, 0);
    stgB(1, 0, 0);
    stgB(2, 0, 0);
    stgA(0, 1, 1);
    asm volatile("s_waitcnt vmcnt(2)");
    __builtin_amdgcn_s_barrier();
    {
#pragma unroll
      for (int mi = 0; mi < 4; ++mi) af2[0][mi] = *(const s16x8*)(aB0 + mi * 1024);
#pragma unroll
      for (int ni = 0; ni < 3; ++ni) bk2[0][ni] = *(const s16x8*)(bKH0 + ni * 2048);
    }

    for (int t = 0; t + 3 < NT; t += 2) {
      gphP<0, 0, 0, 0, 1, 0, 0, -1, 0>(aB0, bKH0, bKH1, af2, bk2, acc,
          [&] { stgA(1, 1, t + 1); stgB(0, 1, t + 1); stgB(1, 1, t + 1); });
      gphP<1, 1, 0, 0, 0, 1, 1, -1, 0>(aB0, bKH0, bKH1, af2, bk2, acc,
          [&] { stgB(2, 1, t + 1); });
      gphP<0, 0, 1, 0, 1, 1, 0, -1, 0>(aB0, bKH0, bKH1, af2, bk2, acc,
          [&] { stgA(0, 0, t + 2); });
      gphP<1, 1, 1, 1, 0, 0, 0, 2, 0>(aB0, bKH0, bKH1, af2, bk2, acc, nop);
      gphP<0, 0, 0, 1, 1, 0, 0, -1, 0>(aB0, bKH0, bKH1, af2, bk2, acc,
          [&] { stgA(1, 0, t + 2); stgB(0, 0, t + 2); stgB(1, 0, t + 2); });
      gphP<1, 1, 0, 1, 0, 1, 1, -1, 0>(aB0, bKH0, bKH1, af2, bk2, acc,
          [&] { stgB(2, 0, t + 2); });
      gphP<0, 0, 1, 1, 1, 1, 0, -1, 0>(aB0, bKH0, bKH1, af2, bk2, acc,
          [&] { stgA(0, 1, t + 3); });
      gphP<1, 1, 1, 0, 0, 0, 0, 2, 0>(aB0, bKH0, bKH1, af2, bk2, acc, nop);
    }
    gphP<0, 0, 0, 0, 1, 0, 0, -1, 0>(aB0, bKH0, bKH1, af2, bk2, acc,
        [&] { stgA(1, 1, NT - 1); stgB(0, 1, NT - 1); stgB(1, 1, NT - 1); });
    gphP<1, 1, 0, 0, 0, 1, 1, -1, 0>(aB0, bKH0, bKH1, af2, bk2, acc,
        [&] { stgB(2, 1, NT - 1); });
    gphP<0, 0, 1, 0, 1, 1, 0, -1, 0>(aB0, bKH0, bKH1, af2, bk2, acc, nop);
    gphP<1, 1, 1, 1, 0, 0, 0, 0, 0>(aB0, bKH0, bKH1, af2, bk2, acc, nop);
    gphP<0, 0, 0, 1, 1, 0, 0, -1, 0>(aB0, bKH0, bKH1, af2, bk2, acc, nop);
    gphP<1, 1, 0, 1, 0, 1, 1, -1, 0>(aB0, bKH0, bKH1, af2, bk2, acc, nop);
    gphP<0, 0, 1, 1, 1, 1, 0, -1, 0>(aB0, bKH0, bKH1, af2, bk2, acc, nop);
    gphP<1, 1, 1, 0, 0, 0, 0, -1, 1>(aB0, bKH0, bKH1, af2, bk2, acc, nop);

#pragma unroll
    for (int am = 0; am < 8; ++am)
#pragma unroll
      for (int ni = 0; ni < 3; ++ni)
#pragma unroll
        for (int rr = 0; rr < 4; ++rr) {
          int row = m0 + wm * 128 + am * 16 + q * 4 + rr;
          int col = n0 + wn * 48 + ni * 16 + fr;
          size_t idx = (size_t)row * N + col;
          epi_store(EPI, outp, idx, epi_apply(EPI, acc[am][ni][rr], col, idx, bias, resid));
        }
  }
}

// ============ pipelined persistent 8-phase 256x256 GEMM (mlp1) ============
// 16 MFMA/phase density test. Staging/ledger = R8-proven gemm8 pattern
// (steady vmcnt(10) @ ph2/4/6/8; epilogue vmcnt(4)@ph4, vmcnt(0)@ph6);
// frag reads pipelined one phase ahead (R15-proven). LDS 128KB:
// [buf(2)][A@0 | B@65536][kh(2)][256][32].
template <int CMH, int CS, int CB, int RBUF, int RMH, int RKH, int RB, int VM, int NORD,
          typename STF>
__device__ __forceinline__ void gphQ(const char* aB0, const char* bB0,
                                     s16x8 (&af2)[2][4], s16x8 (&bk2)[2][4],
                                     f32x4 (&acc)[8][4], STF&& stage) {
  stage();
  if (VM == 10) asm volatile("s_waitcnt vmcnt(10)");
  if (VM == 4) asm volatile("s_waitcnt vmcnt(4)");
  if (VM == 0) asm volatile("s_waitcnt vmcnt(0)");
  __builtin_amdgcn_s_barrier();
  if (!NORD) {
    const char* aP = aB0 + RBUF * 32768 + RKH * 16384 + RMH * 4096;
#pragma unroll
    for (int mi = 0; mi < 4; ++mi) af2[CS ^ 1][mi] = *(const s16x8*)(aP + mi * 1024);
    if (RMH == 0) {
      const char* bP = bB0 + RBUF * 32768 + RKH * 16384;
#pragma unroll
      for (int ni = 0; ni < 4; ++ni) bk2[RB][ni] = *(const s16x8*)(bP + ni * 1024);
    }
  }
  __builtin_amdgcn_s_setprio(1);
#pragma unroll
  for (int mi = 0; mi < 4; ++mi)
#pragma unroll
    for (int ni = 0; ni < 4; ++ni)
      acc[CMH * 4 + mi][ni] = __builtin_amdgcn_mfma_f32_16x16x32_bf16(
          af2[CS][mi], bk2[CB][ni], acc[CMH * 4 + mi][ni], 0, 0, 0);
  __builtin_amdgcn_s_setprio(0);
  __builtin_amdgcn_s_barrier();
}

template <int EPI, int TPB>
__device__ __forceinline__ void gemm256_body(
    const unsigned short* __restrict__ A, const unsigned short* __restrict__ Bt,
    void* __restrict__ outp, const float* __restrict__ bias,
    const void* __restrict__ resid, int M, int N, int K, int ntn) {
  __shared__ char ldsc[131072];  // 128 KiB
  int tid = threadIdx.x;
  int lane = tid & 63, w = tid >> 6;
  int wm = w >> 2, wn = w & 3;
  int fr = lane & 15, q = lane >> 4;

  int nwg = gridDim.x, orig = blockIdx.x;
  int qd = nwg >> 3, r8 = nwg & 7, xcd = orig & 7, loc = orig >> 3;
  int bid = (xcd < r8 ? xcd * (qd + 1) : r8 * (qd + 1) + (xcd - r8) * qd) + loc;

  int rdoff = (q * 16) ^ (((fr >> 1) & 3) << 4);
  const char* aB0 = ldsc + (wm * 128 + fr) * 64 + rdoff;
  const char* bB0 = ldsc + 65536 + (wn * 64 + fr) * 64 + rdoff;

  int srow = tid >> 2;
  int seoff = (((tid & 3) ^ ((srow >> 1) & 3))) << 3;
  size_t rstep = (size_t)K * 256;
  int NT = K / 64;

#pragma unroll 1
  for (int tl = 0; tl < TPB; ++tl) {
    int tile = bid * TPB + tl;
    int m0 = (tile / ntn) * 256, n0 = (tile % ntn) * 256;

    const char* Ab = (const char*)A + ((size_t)(m0 + srow) * K + seoff) * 2;
    const char* Bb = (const char*)Bt + ((size_t)(n0 + srow) * K + seoff) * 2;

    // mat: 0=A, 1=B; LDS [buf][mat][kh][256][32]
    auto stg = [&](int mat, int kh, int buf, int t) {
      const char* gp = (mat ? Bb : Ab) + t * 128 + kh * 64;
      unsigned short* lp =
          (unsigned short*)(ldsc + mat * 65536 + buf * 32768 + kh * 16384 + w * 1024);
      gload16((const unsigned short*)gp, lp);
      gload16((const unsigned short*)(gp + rstep), (unsigned short*)((char*)lp + 8192));
    };
    auto nop = [&] {};

    f32x4 acc[8][4] = {};
    s16x8 af2[2][4], bk2[2][4];

    // prologue: t0 full (B0,A0,B1,A1) + t1 {B0,A0,B1}; vmcnt(6) retires t0 (8 loads)
    stg(1, 0, 0, 0);
    stg(0, 0, 0, 0);
    stg(1, 1, 0, 0);
    stg(0, 1, 0, 0);
    stg(1, 0, 1, 1);
    stg(0, 0, 1, 1);
    stg(1, 1, 1, 1);
    asm volatile("s_waitcnt vmcnt(6)");
    __builtin_amdgcn_s_barrier();
    {
#pragma unroll
      for (int mi = 0; mi < 4; ++mi) af2[0][mi] = *(const s16x8*)(aB0 + mi * 1024);
#pragma unroll
      for (int ni = 0; ni < 4; ++ni) bk2[0][ni] = *(const s16x8*)(bB0 + ni * 1024);
    }

    for (int t = 0; t + 3 < NT; t += 2) {
      gphQ<0, 0, 0, 0, 1, 0, 0, -1, 0>(aB0, bB0, af2, bk2, acc,
          [&] { stg(0, 1, 1, t + 1); });
      gphQ<1, 1, 0, 0, 0, 1, 1, 10, 0>(aB0, bB0, af2, bk2, acc,
          [&] { stg(1, 0, 0, t + 2); });
      gphQ<0, 0, 1, 0, 1, 1, 0, -1, 0>(aB0, bB0, af2, bk2, acc,
          [&] { stg(0, 0, 0, t + 2); });
      gphQ<1, 1, 1, 1, 0, 0, 0, 10, 0>(aB0, bB0, af2, bk2, acc,
          [&] { stg(1, 1, 0, t + 2); });
      gphQ<0, 0, 0, 1, 1, 0, 0, -1, 0>(aB0, bB0, af2, bk2, acc,
          [&] { stg(0, 1, 0, t + 2); });
      gphQ<1, 1, 0, 1, 0, 1, 1, 10, 0>(aB0, bB0, af2, bk2, acc,
          [&] { stg(1, 0, 1, t + 3); });
      gphQ<0, 0, 1, 1, 1, 1, 0, -1, 0>(aB0, bB0, af2, bk2, acc,
          [&] { stg(0, 0, 1, t + 3); });
      gphQ<1, 1, 1, 0, 0, 0, 0, 10, 0>(aB0, bB0, af2, bk2, acc,
          [&] { stg(1, 1, 1, t + 3); });
    }
    // epilogue: tiles NT-2, NT-1; outstanding after ph1 = 8 loads
    gphQ<0, 0, 0, 0, 1, 0, 0, -1, 0>(aB0, bB0, af2, bk2, acc,
        [&] { stg(0, 1, 1, NT - 1); });
    gphQ<1, 1, 0, 0, 0, 1, 1, -1, 0>(aB0, bB0, af2, bk2, acc, nop);
    gphQ<0, 0, 1, 0, 1, 1, 0, -1, 0>(aB0, bB0, af2, bk2, acc, nop);
    gphQ<1, 1, 1, 1, 0, 0, 0, 4, 0>(aB0, bB0, af2, bk2, acc, nop);
    gphQ<0, 0, 0, 1, 1, 0, 0, -1, 0>(aB0, bB0, af2, bk2, acc, nop);
    gphQ<1, 1, 0, 1, 0, 1, 1, 0, 0>(aB0, bB0, af2, bk2, acc, nop);
    gphQ<0, 0, 1, 1, 1, 1, 0, -1, 0>(aB0, bB0, af2, bk2, acc, nop);
    gphQ<1, 1, 1, 0, 0, 0, 0, -1, 1>(aB0, bB0, af2, bk2, acc, nop);

#pragma unroll
    for (int am = 0; am < 8; ++am)
#pragma unroll
      for (int ni = 0; ni < 4; ++ni)
#pragma unroll
        for (int rr = 0; rr < 4; ++rr) {
          int row = m0 + wm * 128 + am * 16 + q * 4 + rr;
          int col = n0 + wn * 64 + ni * 16 + fr;
          size_t idx = (size_t)row * N + col;
          epi_store(EPI, outp, idx, epi_apply(EPI, acc[am][ni][rr], col, idx, bias, resid));
        }
  }
}

// named wrappers for rocprof attribution
__global__ __launch_bounds__(512, 2) void gemm_qkv(const unsigned short* A,
                                                   const unsigned short* Bt, void* o,
                                                   const float* b, const void* r, int M,
                                                   int N, int K, int ntn) {
  gemm192_body<0, 3>(A, Bt, o, b, r, M, N, K, ntn);
}
__global__ __launch_bounds__(512, 2) void gemm_mlp1(const unsigned short* A,
                                                    const unsigned short* Bt, void* o,
                                                    const float* b, const void* r, int M,
                                                    int N, int K, int ntn) {
  gemm256_body<2, 3>(A, Bt, o, b, r, M, N, K, ntn);
}
__global__ __launch_bounds__(512, 2) void gemm_proj(const unsigned short* A,
                                                    const unsigned short* Bt, void* o,
                                                    const float* b, const void* r, int M,
                                                    int N, int K, int ntn) {
  gemm192_body<3, 1>(A, Bt, o, b, r, M, N, K, ntn);
}
__global__ __launch_bounds__(512, 2) void gemm_mlp2(const unsigned short* A,
                                                    const unsigned short* Bt, void* o,
                                                    const float* b, const void* r, int M,
                                                    int N, int K, int ntn) {
  gemm192_body<4, 1>(A, Bt, o, b, r, M, N, K, ntn);
}

// ---------------- MFMA attention: one wave per (batch, head) ----------------
__global__ __launch_bounds__(256) void attn_mfma_kernel(const unsigned short* __restrict__ qkv,
                                                        const float* __restrict__ scale,
                                                        unsigned short* __restrict__ ao) {
  __shared__ unsigned short Vt[4][64][40];
  __shared__ unsigned short Pl[4][32][32];
  int wid = threadIdx.x >> 6, lane = threadIdx.x & 63;
  int pair = blockIdx.x * 4 + wid;
  int b = pair / HEADS, h = pair % HEADS;
  const unsigned short* base = qkv + (size_t)b * NTOK * QKVN + h * DHEAD;
  const unsigned short* Qp = base;
  const unsigned short* Kp = base + 768;
  const unsigned short* Vp = base + 1536;

  int c = lane & 15, q = lane >> 4;
  int oct = q * 8;

  unsigned short vcol[NTOK];
#pragma unroll
  for (int j = 0; j < NTOK; ++j) vcol[j] = Vp[(size_t)j * QKVN + lane];
#pragma unroll
  for (int j = 0; j < NTOK; ++j) Vt[wid][lane][j] = vcol[j];
  Vt[wid][lane][31] = 0;

  s16x8 kf[2][2] = {{{0}}}, qf[2][2] = {{{0}}};
#pragma unroll
  for (int t = 0; t < 2; ++t) {
    int row = t * 16 + c;
    if (row < NTOK) {
#pragma unroll
      for (int s = 0; s < 2; ++s) {
        kf[t][s] = *(const s16x8*)(Kp + (size_t)row * QKVN + s * 32 + oct);
        qf[t][s] = *(const s16x8*)(Qp + (size_t)row * QKVN + s * 32 + oct);
      }
    }
  }

  f32x4 st[2][2] = {};
#pragma unroll
  for (int jt = 0; jt < 2; ++jt)
#pragma unroll
    for (int it = 0; it < 2; ++it)
#pragma unroll
      for (int s = 0; s < 2; ++s)
        st[jt][it] =
            __builtin_amdgcn_mfma_f32_16x16x32_bf16(kf[jt][s], qf[it][s], st[jt][it], 0, 0, 0);

  float scl = scale[h];
  float p[2][2][4];
#pragma unroll
  for (int it = 0; it < 2; ++it)
#pragma unroll
    for (int jt = 0; jt < 2; ++jt)
#pragma unroll
      for (int r = 0; r < 4; ++r) {
        int j = jt * 16 + 4 * q + r;
        int i = it * 16 + c;
        float v = st[jt][it][r] * scl;
        if (j == 31 || j == i) v = MASK_VAL;
        p[it][jt][r] = v;
      }
#pragma unroll
  for (int it = 0; it < 2; ++it) {
    float m = p[it][0][0];
#pragma unroll
    for (int jt = 0; jt < 2; ++jt)
#pragma unroll
      for (int r = 0; r < 4; ++r) m = fmaxf(m, p[it][jt][r]);
    m = fmaxf(m, __shfl_xor(m, 16));
    m = fmaxf(m, __shfl_xor(m, 32));
    float s = 0.f;
#pragma unroll
    for (int jt = 0; jt < 2; ++jt)
#pragma unroll
      for (int r = 0; r < 4; ++r) {
        float e = __expf(p[it][jt][r] - m);
        p[it][jt][r] = e;
        s += e;
      }
    s += __shfl_xor(s, 16);
    s += __shfl_xor(s, 32);
    float inv = __builtin_amdgcn_rcpf(s);
#pragma unroll
    for (int jt = 0; jt < 2; ++jt)
#pragma unroll
      for (int r = 0; r < 4; ++r) p[it][jt][r] *= inv;
  }
#pragma unroll
  for (int it = 0; it < 2; ++it)
#pragma unroll
    for (int jt = 0; jt < 2; ++jt) {
      unsigned int w0 =
          (unsigned int)f2bs(p[it][jt][0]) | ((unsigned int)f2bs(p[it][jt][1]) << 16);
      unsigned int w1 =
          (unsigned int)f2bs(p[it][jt][2]) | ((unsigned int)f2bs(p[it][jt][3]) << 16);
      uint2 pk = {w0, w1};
      *(uint2*)&Pl[wid][it * 16 + c][jt * 16 + 4 * q] = pk;
    }

  s16x8 pa[2];
#pragma unroll
  for (int it = 0; it < 2; ++it) pa[it] = *(const s16x8*)&Pl[wid][it * 16 + c][oct];
  f32x4 o[2][4];
#pragma unroll
  for (int it = 0; it < 2; ++it)
#pragma unroll
    for (int dt = 0; dt < 4; ++dt) {
      s16x8 vb = *(const s16x8*)&Vt[wid][dt * 16 + c][oct];
      f32x4 z = {0.f, 0.f, 0.f, 0.f};
      o[it][dt] = __builtin_amdgcn_mfma_f32_16x16x32_bf16(pa[it], vb, z, 0, 0, 0);
    }
#pragma unroll
  for (int it = 0; it < 2; ++it)
#pragma unroll
    for (int r = 0; r < 4; ++r) {
      int i = it * 16 + 4 * q + r;
      if (i < NTOK) {
        size_t rowoff = ((size_t)b * NTOK + i) * DIM + h * DHEAD;
#pragma unroll
        for (int dt = 0; dt < 4; ++dt) ao[rowoff + dt * 16 + c] = f2bs(o[it][dt][r]);
      }
    }
}

// ---------------- launcher ----------------
extern "C" void kernel_launch(void* const* d_in, const int* in_sizes, int n_in,
                              void* d_out, int out_size, void* d_ws, size_t ws_size,
                              hipStream_t stream) {
  (void)in_sizes; (void)n_in; (void)out_size; (void)ws_size;
  const float* x = (const float*)d_in[0];
  const float* ln1_g = (const float*)d_in[1];
  const float* ln1_b = (const float*)d_in[2];
  const float* w_qkv = (const float*)d_in[3];
  const float* scale = (const float*)d_in[4];
  const float* w_o = (const float*)d_in[5];
  const float* b_o = (const float*)d_in[6];
  const float* ln2_g = (const float*)d_in[7];
  const float* ln2_b = (const float*)d_in[8];
  const float* w1 = (const float*)d_in[9];
  const float* b1 = (const float*)d_in[10];
  const float* w2 = (const float*)d_in[11];
  const float* b2 = (const float*)d_in[12];

  char* ws = (char*)d_ws;
  unsigned short* buf1 = (unsigned short*)(ws + 0);
  unsigned short* qkv_bf = (unsigned short*)(ws + 24379392);
  unsigned short* x2 = (unsigned short*)(ws + 24379392);  // aliases qkv (qkv dead)
  unsigned short* g_bf = (unsigned short*)(ws + 97517568);
  unsigned short* wqkvT = (unsigned short*)(ws + 195035136);  // flat [2304][768]
  unsigned short* woT = (unsigned short*)(ws + 198574080);    // flat [768][768]
  unsigned short* w1T = (unsigned short*)(ws + 199753728);    // flat [3072][768]
  unsigned short* w2T = (unsigned short*)(ws + 204472320);    // flat [768][3072]

  transpose_all_kernel<<<1728, 256, 0, stream>>>(w_qkv, w_o, w1, w2, wqkvT, woT, w1T, w2T);

  ln_kernel<<<MTOK / 4, 256, 0, stream>>>(x, ln1_g, ln1_b, buf1);
  // qkv GEMM   [256x192, 744 tiles, TPB=3 -> grid 248]
  gemm_qkv<<<248, 512, 0, stream>>>(
      buf1, wqkvT, qkv_bf, nullptr, nullptr, MTOK, QKVN, DIM, QKVN / 192);
  attn_mfma_kernel<<<(BATCH * HEADS) / 4, 256, 0, stream>>>(qkv_bf, scale, buf1);
  // proj + residual(x, f32) -> x2 (bf16)   [248 tiles, TPB=1]
  gemm_proj<<<248, 512, 0, stream>>>(
      buf1, woT, x2, b_o, x, MTOK, DIM, DIM, DIM / 192);
  ln_bf16_kernel<<<MTOK / 4, 256, 0, stream>>>(x2, ln2_g, ln2_b, buf1);
  // mlp1 + tanh-GELU   [256x256, 744 tiles, TPB=3 -> grid 248]
  gemm_mlp1<<<248, 512, 0, stream>>>(
      buf1, w1T, g_bf, b1, nullptr, MTOK, HIDDEN, DIM, HIDDEN / 256);
  // mlp2 + residual(x2, bf16) -> out (f32)   [248 tiles, TPB=1]
  gemm_mlp2<<<248, 512, 0, stream>>>(
      g_bf, w2T, (float*)d_out, b2, x2, MTOK, DIM, HIDDEN, DIM / 192);
}